// Round 11
// baseline (1911.774 us; speedup 1.0000x reference)
//
#include <hip/hip_runtime.h>
#include <hip/hip_bf16.h>

// LightGCN propagation, 3 bipartite graphs. Round 9: XCD-local CSR atomics.
// Evidence (r1 vs r8): fire-and-forget atomics run ~75G/s, but the scatter's
// fetch-add NEEDS its return -> device-scope round-trip to memory-side
// (per-XCD L2s non-coherent) stalls every edge ~600-900cy. Fix: per-(node,
// XCD) counters/cursors indexed node*8+XCC_ID, so each counter is touched by
// ONE die only -> workgroup-scope atomic = L2-local RMW (8 L2s in parallel,
// ~4x lower latency). Scan over node-major/xcc-minor counters yields an
// EXACT CSR with per-row-contiguous ci (no padding); spmm reads
// ptr8[n*8]..ptr8[n*8+8]. Union-graph + bf16 features kept from r7/r8.

constexpr int EMB = 64;
constexpr int NXCD = 8;
constexpr float THIRD = 1.0f / 3.0f;
constexpr float EPS_NRM = 1e-12f;
constexpr float EPS_LAP = 1e-8f;
constexpr int SCAN_BLOCK = 256;
constexpr int SCAN_ITEMS = 16;       // = 2 nodes' worth of (node,xcd) counters
constexpr int SCAN_TILE = SCAN_BLOCK * SCAN_ITEMS;  // 4096

__device__ __forceinline__ unsigned short f2b(float x) {
    __hip_bfloat16 h = __float2bfloat16(x);
    return *reinterpret_cast<unsigned short*>(&h);
}
__device__ __forceinline__ float b2f(unsigned short u) {
    return __uint_as_float(((unsigned)u) << 16);
}
__device__ __forceinline__ int xcc_id() {
    unsigned x;
    asm volatile("s_getreg_b32 %0, hwreg(HW_REG_XCC_ID)" : "=s"(x));
    return (int)(x & (NXCD - 1));
}
__device__ __forceinline__ int fadd_local(int* p) {
    return __hip_atomic_fetch_add(p, 1, __ATOMIC_RELAXED,
                                  __HIP_MEMORY_SCOPE_WORKGROUP);
}

// 1 thread per directed edge; bump cnt8[node*8 + xcc] (L2-local, no return).
__global__ void hist3_kernel(const int* __restrict__ r0, const int* __restrict__ c0,
                             const int* __restrict__ r1, const int* __restrict__ c1,
                             const int* __restrict__ r2, const int* __restrict__ c2,
                             long long H0, long long H01, long long H,
                             int off1, int off2,
                             int* __restrict__ cnt) {
    long long t = blockIdx.x * (long long)blockDim.x + threadIdx.x;
    if (t >= 2 * H) return;
    const bool second = (t >= H);
    long long p = second ? t - H : t;
    int node;
    if (p < H0)       { node = second ? c0[p] : r0[p]; }
    else if (p < H01) { long long i = p - H0;  node = (second ? c1[i] : r1[i]) + off1; }
    else              { long long i = p - H01; node = (second ? c2[i] : r2[i]) + off2; }
    (void)fadd_local(&cnt[(long long)node * NXCD + xcc_id()]);
}

// --- two-level scan over N8 = Ntot*8 (node,xcd) counters --------------------
__global__ void scan_partial_kernel(const int* __restrict__ cnt, int N8,
                                    int* __restrict__ bsum) {
    __shared__ int red[SCAN_BLOCK];
    const int b = blockIdx.x;
    const int t = threadIdx.x;
    const int base = b * SCAN_TILE + t * SCAN_ITEMS;
    int s = 0;
    if (base + SCAN_ITEMS <= N8) {
        #pragma unroll
        for (int q = 0; q < 4; ++q) {
            int4 a = ((const int4*)cnt)[(base >> 2) + q];
            s += a.x + a.y + a.z + a.w;
        }
    } else {
        for (int k = 0; k < SCAN_ITEMS; ++k)
            if (base + k < N8) s += cnt[base + k];
    }
    red[t] = s;
    __syncthreads();
    for (int off = SCAN_BLOCK / 2; off > 0; off >>= 1) {
        if (t < off) red[t] += red[t + off];
        __syncthreads();
    }
    if (t == 0) bsum[b] = red[0];
}

__global__ void scan_bsums_kernel(int* __restrict__ bsum, int NB) {
    __shared__ int s[1024];
    const int t = threadIdx.x;
    int v = (t < NB) ? bsum[t] : 0;
    s[t] = v;
    __syncthreads();
    for (int off = 1; off < 1024; off <<= 1) {
        int x = (t >= off) ? s[t - off] : 0;
        __syncthreads();
        s[t] += x;
        __syncthreads();
    }
    if (t < NB) bsum[t] = s[t] - v;      // exclusive prefix
    if (t == 1023) bsum[NB] = s[1023];   // total
}

// Exclusive scan + cursor init; each thread owns exactly 2 nodes (16
// counters), so per-node degree = local 8-sum -> isq computed here.
__global__ void scan_apply_kernel(int* __restrict__ cnt, int N8,
                                  const int* __restrict__ bsum, int NB,
                                  int* __restrict__ ptr,
                                  float* __restrict__ isq) {
    __shared__ int tsum[SCAN_BLOCK];
    const int b = blockIdx.x;
    const int t = threadIdx.x;
    const int base = b * SCAN_TILE + t * SCAN_ITEMS;
    int v[SCAN_ITEMS];
    int s = 0;
    if (base + SCAN_ITEMS <= N8) {
        #pragma unroll
        for (int q = 0; q < 4; ++q) {
            int4 a = ((const int4*)cnt)[(base >> 2) + q];
            v[4 * q + 0] = a.x; v[4 * q + 1] = a.y;
            v[4 * q + 2] = a.z; v[4 * q + 3] = a.w;
        }
        #pragma unroll
        for (int k = 0; k < SCAN_ITEMS; ++k) s += v[k];
    } else {
        for (int k = 0; k < SCAN_ITEMS; ++k) {
            v[k] = (base + k < N8) ? cnt[base + k] : 0;
            s += v[k];
        }
    }
    tsum[t] = s;
    __syncthreads();
    for (int off = 1; off < SCAN_BLOCK; off <<= 1) {
        int x = (t >= off) ? tsum[t - off] : 0;
        __syncthreads();
        tsum[t] += x;
        __syncthreads();
    }
    int run = bsum[b] + tsum[t] - s;
    for (int k = 0; k < SCAN_ITEMS; ++k) {
        if (base + k < N8) {
            ptr[base + k] = run;
            cnt[base + k] = run;         // scatter cursor
            run += v[k];
        }
    }
    // base is a multiple of 16 and N8 a multiple of 8 -> full-node chunks.
    if (base < N8) {
        int d0 = v[0] + v[1] + v[2] + v[3] + v[4] + v[5] + v[6] + v[7];
        isq[base >> 3] = 1.0f / (sqrtf((float)d0) + EPS_LAP);
    }
    if (base + 8 < N8) {
        int d1 = v[8] + v[9] + v[10] + v[11] + v[12] + v[13] + v[14] + v[15];
        isq[(base >> 3) + 1] = 1.0f / (sqrtf((float)d1) + EPS_LAP);
    }
    if (b == 0 && t == 0) ptr[N8] = bsum[NB];
}
// ----------------------------------------------------------------------------

// 1 thread per directed edge: L2-local fetch-add on the (row,xcc) cursor +
// 1 scattered store. Positions are globally unique and row-contiguous.
__global__ void scatter3_kernel(const int* __restrict__ r0, const int* __restrict__ c0,
                                const int* __restrict__ r1, const int* __restrict__ c1,
                                const int* __restrict__ r2, const int* __restrict__ c2,
                                long long H0, long long H01, long long H,
                                int off1, int off2,
                                int* __restrict__ cursor,
                                int* __restrict__ ci) {
    long long t = blockIdx.x * (long long)blockDim.x + threadIdx.x;
    if (t >= 2 * H) return;
    const bool second = (t >= H);
    long long p = second ? t - H : t;
    int a, b;
    if (p < H0)       { a = r0[p];                  b = c0[p]; }
    else if (p < H01) { long long i = p - H0;  a = r1[i] + off1; b = c1[i] + off1; }
    else              { long long i = p - H01; a = r2[i] + off2; b = c2[i] + off2; }
    int row = second ? b : a;
    int col = second ? a : b;
    int pos = fadd_local(&cursor[(long long)row * NXCD + xcc_id()]);
    ci[pos] = col;
}

// Union init: node n -> (graph, A/B feature source). curS = bf16(isq*x);
// acc = x/3 (fp32, directly in d_out).
__global__ void init3_kernel(const float4* __restrict__ fu,
                             const float4* __restrict__ fb,
                             const float4* __restrict__ fi,
                             int nU, int nB, int nI,
                             int off1, int off2, int Ntot,
                             const float* __restrict__ isq,
                             ushort4* __restrict__ curS,
                             float4* __restrict__ acc) {
    long long total = (long long)Ntot * 16;
    long long i = blockIdx.x * (long long)blockDim.x + threadIdx.x;
    if (i >= total) return;
    int n = (int)(i >> 4);
    int ch = (int)(i & 15);
    float4 v;
    if (n < off1) {
        v = (n < nU) ? fu[(long long)n * 16 + ch]
                     : fb[(long long)(n - nU) * 16 + ch];
    } else if (n < off2) {
        int l = n - off1;
        v = (l < nU) ? fu[(long long)l * 16 + ch]
                     : fi[(long long)(l - nU) * 16 + ch];
    } else {
        int l = n - off2;
        v = (l < nB) ? fb[(long long)l * 16 + ch]
                     : fi[(long long)(l - nB) * 16 + ch];
    }
    float q = isq[n];
    curS[i] = make_ushort4(f2b(v.x * q), f2b(v.y * q), f2b(v.z * q), f2b(v.w * q));
    acc[i] = make_float4(v.x * THIRD, v.y * THIRD, v.z * THIRD, v.w * THIRD);
}

// One wave per union row; lane owns one dim. bf16 gathers (fp32 accumulate),
// 4-way unrolled; fused row-L2-norm + acc update; optional bf16 nxtS write.
// Row range: ptr8[n*8] .. ptr8[n*8+8].
__global__ void spmm_norm_kernel(const int* __restrict__ ptr8,
                                 const int* __restrict__ ci,
                                 const float* __restrict__ isq,
                                 const unsigned short* __restrict__ curS,
                                 unsigned short* __restrict__ nxtS,
                                 float* __restrict__ acc,
                                 int N, int writeNext) {
    int gid = (int)((blockIdx.x * (long long)blockDim.x + threadIdx.x) >> 6);
    int lane = threadIdx.x & 63;
    if (gid >= N) return;
    const int beg = ptr8[(long long)gid * NXCD];
    const int end = ptr8[(long long)gid * NXCD + NXCD];
    float s = 0.0f;
    int j = beg;
    for (; j + 4 <= end; j += 4) {
        int c0 = ci[j];
        int c1 = ci[j + 1];
        int c2 = ci[j + 2];
        int c3 = ci[j + 3];
        float g0 = b2f(curS[(long long)c0 * EMB + lane]);
        float g1 = b2f(curS[(long long)c1 * EMB + lane]);
        float g2 = b2f(curS[(long long)c2 * EMB + lane]);
        float g3 = b2f(curS[(long long)c3 * EMB + lane]);
        s += g0 + g1 + g2 + g3;
    }
    for (; j < end; ++j) {
        s += b2f(curS[(long long)ci[j] * EMB + lane]);
    }
    const float q = isq[gid];
    float raw = s * q;
    float ss = raw * raw;
    ss += __shfl_xor(ss, 1, 64);
    ss += __shfl_xor(ss, 2, 64);
    ss += __shfl_xor(ss, 4, 64);
    ss += __shfl_xor(ss, 8, 64);
    ss += __shfl_xor(ss, 16, 64);
    ss += __shfl_xor(ss, 32, 64);
    const long long idx = (long long)gid * EMB + lane;
    if (writeNext) nxtS[idx] = f2b(raw * q);
    float scale = THIRD / fmaxf(sqrtf(ss), EPS_NRM);
    acc[idx] += raw * scale;
}

static inline int grid_for(long long total, int block) {
    long long g = (total + block - 1) / block;
    if (g > (1LL << 20)) g = (1LL << 20);
    if (g < 1) g = 1;
    return (int)g;
}

extern "C" void kernel_launch(void* const* d_in, const int* in_sizes, int n_in,
                              void* d_out, int out_size, void* d_ws, size_t ws_size,
                              hipStream_t stream) {
    const float* fu = (const float*)d_in[0];
    const float* fb = (const float*)d_in[1];
    const float* fi = (const float*)d_in[2];
    const int nU = in_sizes[0] / EMB;
    const int nB = in_sizes[1] / EMB;
    const int nI = in_sizes[2] / EMB;
    float* out = (float*)d_out;

    // Union-graph geometry.
    const int N0 = nU + nB, N1 = nU + nI, N2 = nB + nI;
    const int off1 = N0;
    const int off2 = N0 + N1;
    const int Ntot = N0 + N1 + N2;
    const int N8 = Ntot * NXCD;
    const long long H0 = (long long)in_sizes[3] / 2;
    const long long H1 = (long long)in_sizes[6] / 2;
    const long long H2 = (long long)in_sizes[9] / 2;
    const long long H01 = H0 + H1;
    const long long H = H0 + H1 + H2;
    const int NB_ = (N8 + SCAN_TILE - 1) / SCAN_TILE;

    const int* r0 = (const int*)d_in[3];
    const int* c0 = (const int*)d_in[4];
    const int* r1 = (const int*)d_in[6];
    const int* c1 = (const int*)d_in[7];
    const int* r2 = (const int*)d_in[9];
    const int* c2 = (const int*)d_in[10];

    // Workspace layout (16B-aligned chunks): ~151MB total.
    char* w = (char*)d_ws;
    unsigned short* bufA = (unsigned short*)w;  w += (size_t)Ntot * EMB * sizeof(unsigned short);
    unsigned short* bufB = (unsigned short*)w;  w += (size_t)Ntot * EMB * sizeof(unsigned short);
    int* ptr8 = (int*)w;                        w += (size_t)(N8 + 16) * sizeof(int);
    int* cnt8 = (int*)w;                        w += (size_t)(N8 + 16) * sizeof(int);
    float* isq = (float*)w;                     w += (size_t)((Ntot + 8) & ~7) * sizeof(float);
    int* bsum = (int*)w;                        w += (size_t)((NB_ + 8) & ~7) * sizeof(int);
    int* ci = (int*)w;

    // --- CSR build over the union graph (XCD-local atomics) ---
    hipMemsetAsync(cnt8, 0, (size_t)N8 * sizeof(int), stream);
    hist3_kernel<<<grid_for(2 * H, 256), 256, 0, stream>>>(
        r0, c0, r1, c1, r2, c2, H0, H01, H, off1, off2, cnt8);
    scan_partial_kernel<<<NB_, SCAN_BLOCK, 0, stream>>>(cnt8, N8, bsum);
    scan_bsums_kernel<<<1, 1024, 0, stream>>>(bsum, NB_);
    scan_apply_kernel<<<NB_, SCAN_BLOCK, 0, stream>>>(cnt8, N8, bsum, NB_, ptr8, isq);
    scatter3_kernel<<<grid_for(2 * H, 256), 256, 0, stream>>>(
        r0, c0, r1, c1, r2, c2, H0, H01, H, off1, off2, cnt8, ci);

    // --- init: curS = bf16(isq.*x); acc = x/3 (into d_out) ---
    init3_kernel<<<grid_for((long long)Ntot * 16, 256), 256, 0, stream>>>(
        (const float4*)fu, (const float4*)fb, (const float4*)fi,
        nU, nB, nI, off1, off2, Ntot, isq, (ushort4*)bufA, (float4*)out);

    // --- 2 fused layers over the whole union ---
    unsigned short* cur = bufA;
    unsigned short* nxt = bufB;
    for (int layer = 0; layer < 2; ++layer) {
        int writeNext = (layer + 1 < 2) ? 1 : 0;
        spmm_norm_kernel<<<grid_for((long long)Ntot * EMB, 256), 256, 0, stream>>>(
            ptr8, ci, isq, cur, nxt, out, Ntot, writeNext);
        unsigned short* t = cur; cur = nxt; nxt = t;
    }
}

// Round 12
// 876.826 us; speedup vs baseline: 2.1803x; 2.1803x over previous
//
#include <hip/hip_runtime.h>
#include <hip/hip_bf16.h>

// LightGCN propagation, 3 bipartite graphs. Round 12: bucketed two-pass CSR
// build (radix-by-row-high-bits) replacing the 10M-returning-atomic scatter.
// r8/r11 evidence: per-edge fetch-add + isolated 4B random store ≈ 850us
// regardless of scope/thread-count (WRITE_SIZE 584MB = full line per store).
// New build: LDS bucket histograms -> block slice reservation (~810K
// returning atomics, 12x fewer) -> packed 4B records into bucket slices ->
// per-bucket block does LDS row-hist (deg/isq/ptr) + LDS-cursor scatter into
// its contiguous ci window (line-merged stores). Union graph + bf16 spmm
// kept from r8. Packed edge buffer aliases bufB (dead until spmm layer 0).

constexpr int EMB = 64;
constexpr float THIRD = 1.0f / 3.0f;
constexpr float EPS_NRM = 1e-12f;
constexpr float EPS_LAP = 1e-8f;
constexpr int BWID = 256;            // nodes per bucket (8-bit local row id)
constexpr int MAXBUK = 1536;         // LDS bound: supports Ntot <= 393216
constexpr int EPB = 16384;           // edges per block in count/pass1
constexpr int P1T = 512;             // threads for count/pass1

__device__ __forceinline__ unsigned short f2b(float x) {
    __hip_bfloat16 h = __float2bfloat16(x);
    return *reinterpret_cast<unsigned short*>(&h);
}
__device__ __forceinline__ float b2f(unsigned short u) {
    return __uint_as_float(((unsigned)u) << 16);
}

// Directed edge t in [0,2H): t<H is pair (a->b), t>=H is mirror (b->a).
__device__ __forceinline__ void decode_edge(
        long long t,
        const int* __restrict__ r0, const int* __restrict__ c0,
        const int* __restrict__ r1, const int* __restrict__ c1,
        const int* __restrict__ r2, const int* __restrict__ c2,
        long long H0, long long H01, long long H,
        int off1, int off2, int& src, int& dst) {
    const bool second = (t >= H);
    long long p = second ? t - H : t;
    int a, b;
    if (p < H0)       { a = r0[p];                  b = c0[p]; }
    else if (p < H01) { long long i = p - H0;  a = r1[i] + off1; b = c1[i] + off1; }
    else              { long long i = p - H01; a = r2[i] + off2; b = c2[i] + off2; }
    src = second ? b : a;
    dst = second ? a : b;
}

// Pass 0: per-block LDS bucket histogram -> fire-and-forget global adds.
__global__ __launch_bounds__(P1T) void count_buckets_kernel(
        const int* __restrict__ r0, const int* __restrict__ c0,
        const int* __restrict__ r1, const int* __restrict__ c1,
        const int* __restrict__ r2, const int* __restrict__ c2,
        long long H0, long long H01, long long H, long long E2,
        int off1, int off2, int NBUK,
        int* __restrict__ gBukCnt) {
    __shared__ int lcnt[MAXBUK];
    for (int b = threadIdx.x; b < NBUK; b += blockDim.x) lcnt[b] = 0;
    __syncthreads();
    const long long beg = (long long)blockIdx.x * EPB;
    const long long end = (beg + EPB < E2) ? beg + EPB : E2;
    for (long long t = beg + threadIdx.x; t < end; t += blockDim.x) {
        int src, dst;
        decode_edge(t, r0, c0, r1, c1, r2, c2, H0, H01, H, off1, off2, src, dst);
        atomicAdd(&lcnt[src >> 8], 1);
    }
    __syncthreads();
    for (int b = threadIdx.x; b < NBUK; b += blockDim.x) {
        int c = lcnt[b];
        if (c) atomicAdd(&gBukCnt[b], c);
    }
}

// Scan bucket counts (NBUK <= 2048): bukPtr/gCur exclusive bases; also
// ptr[Ntot] and bukPtr[NBUK] = total.
__global__ void scan_buckets_kernel(const int* __restrict__ gBukCnt, int NBUK,
                                    int Ntot,
                                    int* __restrict__ bukPtr,
                                    int* __restrict__ gCur,
                                    int* __restrict__ ptr) {
    __shared__ int s[1024];
    const int t = threadIdx.x;
    const int i0 = 2 * t, i1 = 2 * t + 1;
    int v0 = (i0 < NBUK) ? gBukCnt[i0] : 0;
    int v1 = (i1 < NBUK) ? gBukCnt[i1] : 0;
    int sum = v0 + v1;
    s[t] = sum;
    __syncthreads();
    for (int off = 1; off < 1024; off <<= 1) {
        int x = (t >= off) ? s[t - off] : 0;
        __syncthreads();
        s[t] += x;
        __syncthreads();
    }
    int base = s[t] - sum;  // exclusive over thread chunks
    if (i0 < NBUK) { bukPtr[i0] = base;      gCur[i0] = base; }
    if (i1 < NBUK) { bukPtr[i1] = base + v0; gCur[i1] = base + v0; }
    if (t == 1023) {
        int tot = s[1023];
        bukPtr[NBUK] = tot;
        ptr[Ntot] = tot;
    }
}

// Pass 1: re-count in LDS, reserve one slice per (block,bucket) via a single
// returning atomic, then scatter packed (localrow<<24 | col) via LDS cursors.
__global__ __launch_bounds__(P1T) void pass1_scatter_kernel(
        const int* __restrict__ r0, const int* __restrict__ c0,
        const int* __restrict__ r1, const int* __restrict__ c1,
        const int* __restrict__ r2, const int* __restrict__ c2,
        long long H0, long long H01, long long H, long long E2,
        int off1, int off2, int NBUK,
        int* __restrict__ gCur,
        unsigned* __restrict__ edgeBuf) {
    __shared__ int lcnt[MAXBUK];
    for (int b = threadIdx.x; b < NBUK; b += blockDim.x) lcnt[b] = 0;
    __syncthreads();
    const long long beg = (long long)blockIdx.x * EPB;
    const long long end = (beg + EPB < E2) ? beg + EPB : E2;
    for (long long t = beg + threadIdx.x; t < end; t += blockDim.x) {
        int src, dst;
        decode_edge(t, r0, c0, r1, c1, r2, c2, H0, H01, H, off1, off2, src, dst);
        atomicAdd(&lcnt[src >> 8], 1);
    }
    __syncthreads();
    for (int b = threadIdx.x; b < NBUK; b += blockDim.x) {
        int c = lcnt[b];
        lcnt[b] = c ? atomicAdd(&gCur[b], c) : 0;   // absolute slice base
    }
    __syncthreads();
    for (long long t = beg + threadIdx.x; t < end; t += blockDim.x) {
        int src, dst;
        decode_edge(t, r0, c0, r1, c1, r2, c2, H0, H01, H, off1, off2, src, dst);
        int pos = atomicAdd(&lcnt[src >> 8], 1);    // LDS cursor (absolute)
        edgeBuf[pos] = ((unsigned)(src & 255) << 24) | (unsigned)dst;
    }
}

// Pass 2: one block per bucket. LDS row-hist -> deg/isq/ptr; LDS scan;
// LDS-cursor scatter of cols into the bucket's contiguous ci window.
__global__ __launch_bounds__(BWID) void pass2_build_kernel(
        const unsigned* __restrict__ edgeBuf,
        const int* __restrict__ bukPtr,
        int NBUK, int Ntot,
        int* __restrict__ ptr, float* __restrict__ isq,
        int* __restrict__ ci) {
    __shared__ int lcnt[BWID];
    __shared__ int lscan[BWID];
    const int b = blockIdx.x;
    const int t = threadIdx.x;
    const int lo = b * BWID;
    lcnt[t] = 0;
    __syncthreads();
    const int sbeg = bukPtr[b];
    const int send = bukPtr[b + 1];
    for (int p = sbeg + t; p < send; p += BWID) {
        unsigned v = edgeBuf[p];
        atomicAdd(&lcnt[v >> 24], 1);
    }
    __syncthreads();
    const int c = lcnt[t];
    lscan[t] = c;
    __syncthreads();
    for (int off = 1; off < BWID; off <<= 1) {
        int x = (t >= off) ? lscan[t - off] : 0;
        __syncthreads();
        lscan[t] += x;
        __syncthreads();
    }
    const int excl = lscan[t] - c;
    const int node = lo + t;
    if (node < Ntot) {
        ptr[node] = sbeg + excl;
        isq[node] = 1.0f / (sqrtf((float)c) + EPS_LAP);
    }
    lcnt[t] = sbeg + excl;   // absolute cursor
    __syncthreads();
    for (int p = sbeg + t; p < send; p += BWID) {
        unsigned v = edgeBuf[p];
        int pos = atomicAdd(&lcnt[v >> 24], 1);
        ci[pos] = (int)(v & 0x00FFFFFFu);
    }
}

// Union init: node n -> (graph, A/B feature source). curS = bf16(isq*x);
// acc = x/3 (fp32, directly in d_out).
__global__ void init3_kernel(const float4* __restrict__ fu,
                             const float4* __restrict__ fb,
                             const float4* __restrict__ fi,
                             int nU, int nB, int nI,
                             int off1, int off2, int Ntot,
                             const float* __restrict__ isq,
                             ushort4* __restrict__ curS,
                             float4* __restrict__ acc) {
    long long total = (long long)Ntot * 16;
    long long i = blockIdx.x * (long long)blockDim.x + threadIdx.x;
    if (i >= total) return;
    int n = (int)(i >> 4);
    int ch = (int)(i & 15);
    float4 v;
    if (n < off1) {
        v = (n < nU) ? fu[(long long)n * 16 + ch]
                     : fb[(long long)(n - nU) * 16 + ch];
    } else if (n < off2) {
        int l = n - off1;
        v = (l < nU) ? fu[(long long)l * 16 + ch]
                     : fi[(long long)(l - nU) * 16 + ch];
    } else {
        int l = n - off2;
        v = (l < nB) ? fb[(long long)l * 16 + ch]
                     : fi[(long long)(l - nB) * 16 + ch];
    }
    float q = isq[n];
    curS[i] = make_ushort4(f2b(v.x * q), f2b(v.y * q), f2b(v.z * q), f2b(v.w * q));
    acc[i] = make_float4(v.x * THIRD, v.y * THIRD, v.z * THIRD, v.w * THIRD);
}

// One wave per union row; lane owns one dim. bf16 gathers (fp32 accumulate),
// 4-way unrolled; fused row-L2-norm + acc update; optional bf16 nxtS write.
__global__ void spmm_norm_kernel(const int* __restrict__ ptr,
                                 const int* __restrict__ ci,
                                 const float* __restrict__ isq,
                                 const unsigned short* __restrict__ curS,
                                 unsigned short* __restrict__ nxtS,
                                 float* __restrict__ acc,
                                 int N, int writeNext) {
    int gid = (int)((blockIdx.x * (long long)blockDim.x + threadIdx.x) >> 6);
    int lane = threadIdx.x & 63;
    if (gid >= N) return;
    const int beg = ptr[gid];
    const int end = ptr[gid + 1];
    float s = 0.0f;
    int j = beg;
    for (; j + 4 <= end; j += 4) {
        int c0 = ci[j];
        int c1 = ci[j + 1];
        int c2 = ci[j + 2];
        int c3 = ci[j + 3];
        float g0 = b2f(curS[(long long)c0 * EMB + lane]);
        float g1 = b2f(curS[(long long)c1 * EMB + lane]);
        float g2 = b2f(curS[(long long)c2 * EMB + lane]);
        float g3 = b2f(curS[(long long)c3 * EMB + lane]);
        s += g0 + g1 + g2 + g3;
    }
    for (; j < end; ++j) {
        s += b2f(curS[(long long)ci[j] * EMB + lane]);
    }
    const float q = isq[gid];
    float raw = s * q;
    float ss = raw * raw;
    ss += __shfl_xor(ss, 1, 64);
    ss += __shfl_xor(ss, 2, 64);
    ss += __shfl_xor(ss, 4, 64);
    ss += __shfl_xor(ss, 8, 64);
    ss += __shfl_xor(ss, 16, 64);
    ss += __shfl_xor(ss, 32, 64);
    const long long idx = (long long)gid * EMB + lane;
    if (writeNext) nxtS[idx] = f2b(raw * q);
    float scale = THIRD / fmaxf(sqrtf(ss), EPS_NRM);
    acc[idx] += raw * scale;
}

static inline int grid_for(long long total, int block) {
    long long g = (total + block - 1) / block;
    if (g > (1LL << 20)) g = (1LL << 20);
    if (g < 1) g = 1;
    return (int)g;
}

extern "C" void kernel_launch(void* const* d_in, const int* in_sizes, int n_in,
                              void* d_out, int out_size, void* d_ws, size_t ws_size,
                              hipStream_t stream) {
    const float* fu = (const float*)d_in[0];
    const float* fb = (const float*)d_in[1];
    const float* fi = (const float*)d_in[2];
    const int nU = in_sizes[0] / EMB;
    const int nB = in_sizes[1] / EMB;
    const int nI = in_sizes[2] / EMB;
    float* out = (float*)d_out;

    // Union-graph geometry.
    const int N0 = nU + nB, N1 = nU + nI, N2 = nB + nI;
    const int off1 = N0;
    const int off2 = N0 + N1;
    const int Ntot = N0 + N1 + N2;
    const long long H0 = (long long)in_sizes[3] / 2;
    const long long H1 = (long long)in_sizes[6] / 2;
    const long long H2 = (long long)in_sizes[9] / 2;
    const long long H01 = H0 + H1;
    const long long H = H0 + H1 + H2;
    const long long E2 = 2 * H;
    const int NBUK = (Ntot + BWID - 1) / BWID;       // 1329 for this problem
    const int NBLK1 = (int)((E2 + EPB - 1) / EPB);   // ~611

    const int* r0 = (const int*)d_in[3];
    const int* c0 = (const int*)d_in[4];
    const int* r1 = (const int*)d_in[6];
    const int* c1 = (const int*)d_in[7];
    const int* r2 = (const int*)d_in[9];
    const int* c2 = (const int*)d_in[10];

    // Workspace layout (16B-aligned chunks), ~131MB:
    //   bufA, bufB: Ntot*64 bf16 ping-pong; edgeBuf (E2 u32, 40MB) ALIASES
    //   bufB (dead until spmm layer 0 writes it). ptr: Ntot+1. isq: Ntot.
    //   gBukCnt/bukPtr/gCur: NBUK(+1). ci: E2 ints.
    char* w = (char*)d_ws;
    unsigned short* bufA = (unsigned short*)w;  w += (size_t)Ntot * EMB * sizeof(unsigned short);
    unsigned short* bufB = (unsigned short*)w;  w += (size_t)Ntot * EMB * sizeof(unsigned short);
    unsigned* edgeBuf = (unsigned*)bufB;        // alias
    int* ptr = (int*)w;                         w += (size_t)((Ntot + 9) & ~7) * sizeof(int);
    float* isq = (float*)w;                     w += (size_t)((Ntot + 8) & ~7) * sizeof(float);
    int* gBukCnt = (int*)w;                     w += (size_t)((NBUK + 9) & ~7) * sizeof(int);
    int* bukPtr = (int*)w;                      w += (size_t)((NBUK + 9) & ~7) * sizeof(int);
    int* gCur = (int*)w;                        w += (size_t)((NBUK + 9) & ~7) * sizeof(int);
    int* ci = (int*)w;

    // --- bucketed CSR build ---
    hipMemsetAsync(gBukCnt, 0, (size_t)NBUK * sizeof(int), stream);
    count_buckets_kernel<<<NBLK1, P1T, 0, stream>>>(
        r0, c0, r1, c1, r2, c2, H0, H01, H, E2, off1, off2, NBUK, gBukCnt);
    scan_buckets_kernel<<<1, 1024, 0, stream>>>(gBukCnt, NBUK, Ntot, bukPtr, gCur, ptr);
    pass1_scatter_kernel<<<NBLK1, P1T, 0, stream>>>(
        r0, c0, r1, c1, r2, c2, H0, H01, H, E2, off1, off2, NBUK, gCur, edgeBuf);
    pass2_build_kernel<<<NBUK, BWID, 0, stream>>>(
        edgeBuf, bukPtr, NBUK, Ntot, ptr, isq, ci);

    // --- init: curS = bf16(isq.*x); acc = x/3 (into d_out) ---
    init3_kernel<<<grid_for((long long)Ntot * 16, 256), 256, 0, stream>>>(
        (const float4*)fu, (const float4*)fb, (const float4*)fi,
        nU, nB, nI, off1, off2, Ntot, isq, (ushort4*)bufA, (float4*)out);

    // --- 2 fused layers over the whole union ---
    unsigned short* cur = bufA;
    unsigned short* nxt = bufB;
    for (int layer = 0; layer < 2; ++layer) {
        int writeNext = (layer + 1 < 2) ? 1 : 0;
        spmm_norm_kernel<<<grid_for((long long)Ntot * EMB, 256), 256, 0, stream>>>(
            ptr, ci, isq, cur, nxt, out, Ntot, writeNext);
        unsigned short* t = cur; cur = nxt; nxt = t;
    }
}

// Round 13
// 572.343 us; speedup vs baseline: 3.3403x; 1.5320x over previous
//
#include <hip/hip_runtime.h>
#include <hip/hip_bf16.h>

// LightGCN propagation, 3 bipartite graphs. Round 13: SpMM re-layout.
// r12 left spmm_norm as 81% of runtime at VALUBusy 52% (issue-bound, not
// HBM-bound). Old layout: 64 lanes x 1 ushort -> ~7 wave-instrs per edge.
// New: 8 rows/wave x 8 lanes/row x ushort8(16B)/lane -> one wave iteration
// serves 8 edges; per-edge cost ~2.5-3 instrs. bf16->f32 = shift/and only.
// CSR build (bucketed two-pass, r12) and union-graph/bf16 scheme unchanged.

constexpr int EMB = 64;
constexpr float THIRD = 1.0f / 3.0f;
constexpr float EPS_NRM = 1e-12f;
constexpr float EPS_LAP = 1e-8f;
constexpr int BWID = 256;            // nodes per bucket (8-bit local row id)
constexpr int MAXBUK = 1536;         // LDS bound: supports Ntot <= 393216
constexpr int EPB = 16384;           // edges per block in count/pass1
constexpr int P1T = 512;             // threads for count/pass1

__device__ __forceinline__ unsigned short f2b(float x) {
    __hip_bfloat16 h = __float2bfloat16(x);
    return *reinterpret_cast<unsigned short*>(&h);
}
__device__ __forceinline__ float b2f(unsigned short u) {
    return __uint_as_float(((unsigned)u) << 16);
}

// Directed edge t in [0,2H): t<H is pair (a->b), t>=H is mirror (b->a).
__device__ __forceinline__ void decode_edge(
        long long t,
        const int* __restrict__ r0, const int* __restrict__ c0,
        const int* __restrict__ r1, const int* __restrict__ c1,
        const int* __restrict__ r2, const int* __restrict__ c2,
        long long H0, long long H01, long long H,
        int off1, int off2, int& src, int& dst) {
    const bool second = (t >= H);
    long long p = second ? t - H : t;
    int a, b;
    if (p < H0)       { a = r0[p];                  b = c0[p]; }
    else if (p < H01) { long long i = p - H0;  a = r1[i] + off1; b = c1[i] + off1; }
    else              { long long i = p - H01; a = r2[i] + off2; b = c2[i] + off2; }
    src = second ? b : a;
    dst = second ? a : b;
}

// Pass 0: per-block LDS bucket histogram -> fire-and-forget global adds.
__global__ __launch_bounds__(P1T) void count_buckets_kernel(
        const int* __restrict__ r0, const int* __restrict__ c0,
        const int* __restrict__ r1, const int* __restrict__ c1,
        const int* __restrict__ r2, const int* __restrict__ c2,
        long long H0, long long H01, long long H, long long E2,
        int off1, int off2, int NBUK,
        int* __restrict__ gBukCnt) {
    __shared__ int lcnt[MAXBUK];
    for (int b = threadIdx.x; b < NBUK; b += blockDim.x) lcnt[b] = 0;
    __syncthreads();
    const long long beg = (long long)blockIdx.x * EPB;
    const long long end = (beg + EPB < E2) ? beg + EPB : E2;
    for (long long t = beg + threadIdx.x; t < end; t += blockDim.x) {
        int src, dst;
        decode_edge(t, r0, c0, r1, c1, r2, c2, H0, H01, H, off1, off2, src, dst);
        atomicAdd(&lcnt[src >> 8], 1);
    }
    __syncthreads();
    for (int b = threadIdx.x; b < NBUK; b += blockDim.x) {
        int c = lcnt[b];
        if (c) atomicAdd(&gBukCnt[b], c);
    }
}

// Scan bucket counts (NBUK <= 2048): bukPtr/gCur exclusive bases; also
// ptr[Ntot] and bukPtr[NBUK] = total.
__global__ void scan_buckets_kernel(const int* __restrict__ gBukCnt, int NBUK,
                                    int Ntot,
                                    int* __restrict__ bukPtr,
                                    int* __restrict__ gCur,
                                    int* __restrict__ ptr) {
    __shared__ int s[1024];
    const int t = threadIdx.x;
    const int i0 = 2 * t, i1 = 2 * t + 1;
    int v0 = (i0 < NBUK) ? gBukCnt[i0] : 0;
    int v1 = (i1 < NBUK) ? gBukCnt[i1] : 0;
    int sum = v0 + v1;
    s[t] = sum;
    __syncthreads();
    for (int off = 1; off < 1024; off <<= 1) {
        int x = (t >= off) ? s[t - off] : 0;
        __syncthreads();
        s[t] += x;
        __syncthreads();
    }
    int base = s[t] - sum;  // exclusive over thread chunks
    if (i0 < NBUK) { bukPtr[i0] = base;      gCur[i0] = base; }
    if (i1 < NBUK) { bukPtr[i1] = base + v0; gCur[i1] = base + v0; }
    if (t == 1023) {
        int tot = s[1023];
        bukPtr[NBUK] = tot;
        ptr[Ntot] = tot;
    }
}

// Pass 1: re-count in LDS, reserve one slice per (block,bucket) via a single
// returning atomic, then scatter packed (localrow<<24 | col) via LDS cursors.
__global__ __launch_bounds__(P1T) void pass1_scatter_kernel(
        const int* __restrict__ r0, const int* __restrict__ c0,
        const int* __restrict__ r1, const int* __restrict__ c1,
        const int* __restrict__ r2, const int* __restrict__ c2,
        long long H0, long long H01, long long H, long long E2,
        int off1, int off2, int NBUK,
        int* __restrict__ gCur,
        unsigned* __restrict__ edgeBuf) {
    __shared__ int lcnt[MAXBUK];
    for (int b = threadIdx.x; b < NBUK; b += blockDim.x) lcnt[b] = 0;
    __syncthreads();
    const long long beg = (long long)blockIdx.x * EPB;
    const long long end = (beg + EPB < E2) ? beg + EPB : E2;
    for (long long t = beg + threadIdx.x; t < end; t += blockDim.x) {
        int src, dst;
        decode_edge(t, r0, c0, r1, c1, r2, c2, H0, H01, H, off1, off2, src, dst);
        atomicAdd(&lcnt[src >> 8], 1);
    }
    __syncthreads();
    for (int b = threadIdx.x; b < NBUK; b += blockDim.x) {
        int c = lcnt[b];
        lcnt[b] = c ? atomicAdd(&gCur[b], c) : 0;   // absolute slice base
    }
    __syncthreads();
    for (long long t = beg + threadIdx.x; t < end; t += blockDim.x) {
        int src, dst;
        decode_edge(t, r0, c0, r1, c1, r2, c2, H0, H01, H, off1, off2, src, dst);
        int pos = atomicAdd(&lcnt[src >> 8], 1);    // LDS cursor (absolute)
        edgeBuf[pos] = ((unsigned)(src & 255) << 24) | (unsigned)dst;
    }
}

// Pass 2: one block per bucket. LDS row-hist -> deg/isq/ptr; LDS scan;
// LDS-cursor scatter of cols into the bucket's contiguous ci window.
__global__ __launch_bounds__(BWID) void pass2_build_kernel(
        const unsigned* __restrict__ edgeBuf,
        const int* __restrict__ bukPtr,
        int NBUK, int Ntot,
        int* __restrict__ ptr, float* __restrict__ isq,
        int* __restrict__ ci) {
    __shared__ int lcnt[BWID];
    __shared__ int lscan[BWID];
    const int b = blockIdx.x;
    const int t = threadIdx.x;
    const int lo = b * BWID;
    lcnt[t] = 0;
    __syncthreads();
    const int sbeg = bukPtr[b];
    const int send = bukPtr[b + 1];
    for (int p = sbeg + t; p < send; p += BWID) {
        unsigned v = edgeBuf[p];
        atomicAdd(&lcnt[v >> 24], 1);
    }
    __syncthreads();
    const int c = lcnt[t];
    lscan[t] = c;
    __syncthreads();
    for (int off = 1; off < BWID; off <<= 1) {
        int x = (t >= off) ? lscan[t - off] : 0;
        __syncthreads();
        lscan[t] += x;
        __syncthreads();
    }
    const int excl = lscan[t] - c;
    const int node = lo + t;
    if (node < Ntot) {
        ptr[node] = sbeg + excl;
        isq[node] = 1.0f / (sqrtf((float)c) + EPS_LAP);
    }
    lcnt[t] = sbeg + excl;   // absolute cursor
    __syncthreads();
    for (int p = sbeg + t; p < send; p += BWID) {
        unsigned v = edgeBuf[p];
        int pos = atomicAdd(&lcnt[v >> 24], 1);
        ci[pos] = (int)(v & 0x00FFFFFFu);
    }
}

// Union init: node n -> (graph, A/B feature source). curS = bf16(isq*x);
// acc = x/3 (fp32, directly in d_out).
__global__ void init3_kernel(const float4* __restrict__ fu,
                             const float4* __restrict__ fb,
                             const float4* __restrict__ fi,
                             int nU, int nB, int nI,
                             int off1, int off2, int Ntot,
                             const float* __restrict__ isq,
                             ushort4* __restrict__ curS,
                             float4* __restrict__ acc) {
    long long total = (long long)Ntot * 16;
    long long i = blockIdx.x * (long long)blockDim.x + threadIdx.x;
    if (i >= total) return;
    int n = (int)(i >> 4);
    int ch = (int)(i & 15);
    float4 v;
    if (n < off1) {
        v = (n < nU) ? fu[(long long)n * 16 + ch]
                     : fb[(long long)(n - nU) * 16 + ch];
    } else if (n < off2) {
        int l = n - off1;
        v = (l < nU) ? fu[(long long)l * 16 + ch]
                     : fi[(long long)(l - nU) * 16 + ch];
    } else {
        int l = n - off2;
        v = (l < nB) ? fb[(long long)l * 16 + ch]
                     : fi[(long long)(l - nB) * 16 + ch];
    }
    float q = isq[n];
    curS[i] = make_ushort4(f2b(v.x * q), f2b(v.y * q), f2b(v.z * q), f2b(v.w * q));
    acc[i] = make_float4(v.x * THIRD, v.y * THIRD, v.z * THIRD, v.w * THIRD);
}

// SpMM: 8 rows per wave, 8 lanes per row, each lane owns 8 dims (ushort8 =
// 16B gather). One wave iteration serves 8 edges. bf16->f32 via shift/and;
// fp32 accumulate in 8 regs; 3 intra-group shfl_xor for the row L2-norm.
__global__ void spmm_norm_kernel(const int* __restrict__ ptr,
                                 const int* __restrict__ ci,
                                 const float* __restrict__ isq,
                                 const unsigned short* __restrict__ curS,
                                 unsigned short* __restrict__ nxtS,
                                 float* __restrict__ acc,
                                 int N, int writeNext) {
    const long long wid = (blockIdx.x * (long long)blockDim.x + threadIdx.x) >> 6;
    const int lane = threadIdx.x & 63;
    const int grp = lane >> 3;          // row group 0..7
    const int sub = lane & 7;           // dim block: dims [sub*8, sub*8+8)
    const int row = (int)(wid * 8 + grp);
    if (row >= N) return;
    const int beg = ptr[row];
    const int end = ptr[row + 1];
    float s0 = 0.f, s1 = 0.f, s2 = 0.f, s3 = 0.f;
    float s4 = 0.f, s5 = 0.f, s6 = 0.f, s7 = 0.f;
    int j = beg;
    for (; j + 2 <= end; j += 2) {
        const int c0 = ci[j];
        const int c1 = ci[j + 1];
        const uint4 v0 = *(const uint4*)(curS + (long long)c0 * EMB + sub * 8);
        const uint4 v1 = *(const uint4*)(curS + (long long)c1 * EMB + sub * 8);
        s0 += __uint_as_float(v0.x << 16);
        s1 += __uint_as_float(v0.x & 0xffff0000u);
        s2 += __uint_as_float(v0.y << 16);
        s3 += __uint_as_float(v0.y & 0xffff0000u);
        s4 += __uint_as_float(v0.z << 16);
        s5 += __uint_as_float(v0.z & 0xffff0000u);
        s6 += __uint_as_float(v0.w << 16);
        s7 += __uint_as_float(v0.w & 0xffff0000u);
        s0 += __uint_as_float(v1.x << 16);
        s1 += __uint_as_float(v1.x & 0xffff0000u);
        s2 += __uint_as_float(v1.y << 16);
        s3 += __uint_as_float(v1.y & 0xffff0000u);
        s4 += __uint_as_float(v1.z << 16);
        s5 += __uint_as_float(v1.z & 0xffff0000u);
        s6 += __uint_as_float(v1.w << 16);
        s7 += __uint_as_float(v1.w & 0xffff0000u);
    }
    if (j < end) {
        const int c0 = ci[j];
        const uint4 v0 = *(const uint4*)(curS + (long long)c0 * EMB + sub * 8);
        s0 += __uint_as_float(v0.x << 16);
        s1 += __uint_as_float(v0.x & 0xffff0000u);
        s2 += __uint_as_float(v0.y << 16);
        s3 += __uint_as_float(v0.y & 0xffff0000u);
        s4 += __uint_as_float(v0.z << 16);
        s5 += __uint_as_float(v0.z & 0xffff0000u);
        s6 += __uint_as_float(v0.w << 16);
        s7 += __uint_as_float(v0.w & 0xffff0000u);
    }
    const float q = isq[row];
    const float r0f = s0 * q, r1f = s1 * q, r2f = s2 * q, r3f = s3 * q;
    const float r4f = s4 * q, r5f = s5 * q, r6f = s6 * q, r7f = s7 * q;
    float ss = r0f * r0f + r1f * r1f + r2f * r2f + r3f * r3f
             + r4f * r4f + r5f * r5f + r6f * r6f + r7f * r7f;
    ss += __shfl_xor(ss, 1, 64);
    ss += __shfl_xor(ss, 2, 64);
    ss += __shfl_xor(ss, 4, 64);
    const long long fbase = (long long)row * EMB + sub * 8;
    if (writeNext) {
        const float qq = q;
        uint4 o;
        o.x = ((unsigned)f2b(r1f * qq) << 16) | f2b(r0f * qq);
        o.y = ((unsigned)f2b(r3f * qq) << 16) | f2b(r2f * qq);
        o.z = ((unsigned)f2b(r5f * qq) << 16) | f2b(r4f * qq);
        o.w = ((unsigned)f2b(r7f * qq) << 16) | f2b(r6f * qq);
        *(uint4*)(nxtS + fbase) = o;
    }
    const float scale = THIRD / fmaxf(sqrtf(ss), EPS_NRM);
    float4* accp = (float4*)(acc + fbase);
    float4 a0 = accp[0];
    float4 a1 = accp[1];
    a0.x += r0f * scale; a0.y += r1f * scale;
    a0.z += r2f * scale; a0.w += r3f * scale;
    a1.x += r4f * scale; a1.y += r5f * scale;
    a1.z += r6f * scale; a1.w += r7f * scale;
    accp[0] = a0;
    accp[1] = a1;
}

static inline int grid_for(long long total, int block) {
    long long g = (total + block - 1) / block;
    if (g > (1LL << 20)) g = (1LL << 20);
    if (g < 1) g = 1;
    return (int)g;
}

extern "C" void kernel_launch(void* const* d_in, const int* in_sizes, int n_in,
                              void* d_out, int out_size, void* d_ws, size_t ws_size,
                              hipStream_t stream) {
    const float* fu = (const float*)d_in[0];
    const float* fb = (const float*)d_in[1];
    const float* fi = (const float*)d_in[2];
    const int nU = in_sizes[0] / EMB;
    const int nB = in_sizes[1] / EMB;
    const int nI = in_sizes[2] / EMB;
    float* out = (float*)d_out;

    // Union-graph geometry.
    const int N0 = nU + nB, N1 = nU + nI, N2 = nB + nI;
    const int off1 = N0;
    const int off2 = N0 + N1;
    const int Ntot = N0 + N1 + N2;
    const long long H0 = (long long)in_sizes[3] / 2;
    const long long H1 = (long long)in_sizes[6] / 2;
    const long long H2 = (long long)in_sizes[9] / 2;
    const long long H01 = H0 + H1;
    const long long H = H0 + H1 + H2;
    const long long E2 = 2 * H;
    const int NBUK = (Ntot + BWID - 1) / BWID;       // 1329 for this problem
    const int NBLK1 = (int)((E2 + EPB - 1) / EPB);   // ~611

    const int* r0 = (const int*)d_in[3];
    const int* c0 = (const int*)d_in[4];
    const int* r1 = (const int*)d_in[6];
    const int* c1 = (const int*)d_in[7];
    const int* r2 = (const int*)d_in[9];
    const int* c2 = (const int*)d_in[10];

    // Workspace layout (16B-aligned chunks), ~131MB:
    //   bufA, bufB: Ntot*64 bf16 ping-pong; edgeBuf (E2 u32, 40MB) ALIASES
    //   bufB (dead until spmm layer 0 writes it). ptr: Ntot+1. isq: Ntot.
    //   gBukCnt/bukPtr/gCur: NBUK(+1). ci: E2 ints.
    char* w = (char*)d_ws;
    unsigned short* bufA = (unsigned short*)w;  w += (size_t)Ntot * EMB * sizeof(unsigned short);
    unsigned short* bufB = (unsigned short*)w;  w += (size_t)Ntot * EMB * sizeof(unsigned short);
    unsigned* edgeBuf = (unsigned*)bufB;        // alias
    int* ptr = (int*)w;                         w += (size_t)((Ntot + 9) & ~7) * sizeof(int);
    float* isq = (float*)w;                     w += (size_t)((Ntot + 8) & ~7) * sizeof(float);
    int* gBukCnt = (int*)w;                     w += (size_t)((NBUK + 9) & ~7) * sizeof(int);
    int* bukPtr = (int*)w;                      w += (size_t)((NBUK + 9) & ~7) * sizeof(int);
    int* gCur = (int*)w;                        w += (size_t)((NBUK + 9) & ~7) * sizeof(int);
    int* ci = (int*)w;

    // --- bucketed CSR build ---
    hipMemsetAsync(gBukCnt, 0, (size_t)NBUK * sizeof(int), stream);
    count_buckets_kernel<<<NBLK1, P1T, 0, stream>>>(
        r0, c0, r1, c1, r2, c2, H0, H01, H, E2, off1, off2, NBUK, gBukCnt);
    scan_buckets_kernel<<<1, 1024, 0, stream>>>(gBukCnt, NBUK, Ntot, bukPtr, gCur, ptr);
    pass1_scatter_kernel<<<NBLK1, P1T, 0, stream>>>(
        r0, c0, r1, c1, r2, c2, H0, H01, H, E2, off1, off2, NBUK, gCur, edgeBuf);
    pass2_build_kernel<<<NBUK, BWID, 0, stream>>>(
        edgeBuf, bukPtr, NBUK, Ntot, ptr, isq, ci);

    // --- init: curS = bf16(isq.*x); acc = x/3 (into d_out) ---
    init3_kernel<<<grid_for((long long)Ntot * 16, 256), 256, 0, stream>>>(
        (const float4*)fu, (const float4*)fb, (const float4*)fi,
        nU, nB, nI, off1, off2, Ntot, isq, (ushort4*)bufA, (float4*)out);

    // --- 2 fused layers over the whole union (8 rows/wave spmm) ---
    unsigned short* cur = bufA;
    unsigned short* nxt = bufB;
    for (int layer = 0; layer < 2; ++layer) {
        int writeNext = (layer + 1 < 2) ? 1 : 0;
        const long long nwaves = ((long long)Ntot + 7) / 8;
        spmm_norm_kernel<<<grid_for(nwaves * 64, 256), 256, 0, stream>>>(
            ptr, ci, isq, cur, nxt, out, Ntot, writeNext);
        unsigned short* t = cur; cur = nxt; nxt = t;
    }
}

// Round 14
// 536.173 us; speedup vs baseline: 3.5656x; 1.0675x over previous
//
#include <hip/hip_runtime.h>
#include <hip/hip_bf16.h>

// LightGCN propagation, 3 bipartite graphs. Round 14: single-write acc +
// deeper gather MLP.
//  * r13 left spmm 61% of runtime at 46% HBM / 33% VALU (latency-ish).
//  * acc was RMW'd per layer (435 MB total). Now: L1 writes nxtS + nrm1 only;
//    final kernel reconstructs raw1 = nxtS/q, re-reads x, writes
//    out = (x + raw1/max(nrm1,eps) + raw2/max(nrm2,eps))/3 ONCE.
//  * init fused into pass2 (writes curS; no acc pass at all).
//  * 4-way unrolled gathers (4 in flight/lane) in both spmm kernels.
// CSR build: bucketed two-pass (r12). Union graph + bf16 features (r7/r13).

constexpr int EMB = 64;
constexpr float THIRD = 1.0f / 3.0f;
constexpr float EPS_NRM = 1e-12f;
constexpr float EPS_LAP = 1e-8f;
constexpr int BWID = 256;            // nodes per bucket (8-bit local row id)
constexpr int MAXBUK = 1536;         // LDS bound: supports Ntot <= 393216
constexpr int EPB = 16384;           // edges per block in count/pass1
constexpr int P1T = 512;             // threads for count/pass1

__device__ __forceinline__ unsigned short f2b(float x) {
    __hip_bfloat16 h = __float2bfloat16(x);
    return *reinterpret_cast<unsigned short*>(&h);
}

// Directed edge t in [0,2H): t<H is pair (a->b), t>=H is mirror (b->a).
__device__ __forceinline__ void decode_edge(
        long long t,
        const int* __restrict__ r0, const int* __restrict__ c0,
        const int* __restrict__ r1, const int* __restrict__ c1,
        const int* __restrict__ r2, const int* __restrict__ c2,
        long long H0, long long H01, long long H,
        int off1, int off2, int& src, int& dst) {
    const bool second = (t >= H);
    long long p = second ? t - H : t;
    int a, b;
    if (p < H0)       { a = r0[p];                  b = c0[p]; }
    else if (p < H01) { long long i = p - H0;  a = r1[i] + off1; b = c1[i] + off1; }
    else              { long long i = p - H01; a = r2[i] + off2; b = c2[i] + off2; }
    src = second ? b : a;
    dst = second ? a : b;
}

// Union feature fetch: node n, float4-chunk ch (0..15).
__device__ __forceinline__ float4 fetch_feat(
        const float4* __restrict__ fu, const float4* __restrict__ fb,
        const float4* __restrict__ fi,
        int nU, int nB, int off1, int off2, int n, int ch) {
    if (n < off1) {
        return (n < nU) ? fu[(long long)n * 16 + ch]
                        : fb[(long long)(n - nU) * 16 + ch];
    } else if (n < off2) {
        int l = n - off1;
        return (l < nU) ? fu[(long long)l * 16 + ch]
                        : fi[(long long)(l - nU) * 16 + ch];
    } else {
        int l = n - off2;
        return (l < nB) ? fb[(long long)l * 16 + ch]
                        : fi[(long long)(l - nB) * 16 + ch];
    }
}

// Pass 0: per-block LDS bucket histogram -> fire-and-forget global adds.
__global__ __launch_bounds__(P1T) void count_buckets_kernel(
        const int* __restrict__ r0, const int* __restrict__ c0,
        const int* __restrict__ r1, const int* __restrict__ c1,
        const int* __restrict__ r2, const int* __restrict__ c2,
        long long H0, long long H01, long long H, long long E2,
        int off1, int off2, int NBUK,
        int* __restrict__ gBukCnt) {
    __shared__ int lcnt[MAXBUK];
    for (int b = threadIdx.x; b < NBUK; b += blockDim.x) lcnt[b] = 0;
    __syncthreads();
    const long long beg = (long long)blockIdx.x * EPB;
    const long long end = (beg + EPB < E2) ? beg + EPB : E2;
    for (long long t = beg + threadIdx.x; t < end; t += blockDim.x) {
        int src, dst;
        decode_edge(t, r0, c0, r1, c1, r2, c2, H0, H01, H, off1, off2, src, dst);
        atomicAdd(&lcnt[src >> 8], 1);
    }
    __syncthreads();
    for (int b = threadIdx.x; b < NBUK; b += blockDim.x) {
        int c = lcnt[b];
        if (c) atomicAdd(&gBukCnt[b], c);
    }
}

// Scan bucket counts (NBUK <= 2048).
__global__ void scan_buckets_kernel(const int* __restrict__ gBukCnt, int NBUK,
                                    int Ntot,
                                    int* __restrict__ bukPtr,
                                    int* __restrict__ gCur,
                                    int* __restrict__ ptr) {
    __shared__ int s[1024];
    const int t = threadIdx.x;
    const int i0 = 2 * t, i1 = 2 * t + 1;
    int v0 = (i0 < NBUK) ? gBukCnt[i0] : 0;
    int v1 = (i1 < NBUK) ? gBukCnt[i1] : 0;
    int sum = v0 + v1;
    s[t] = sum;
    __syncthreads();
    for (int off = 1; off < 1024; off <<= 1) {
        int x = (t >= off) ? s[t - off] : 0;
        __syncthreads();
        s[t] += x;
        __syncthreads();
    }
    int base = s[t] - sum;
    if (i0 < NBUK) { bukPtr[i0] = base;      gCur[i0] = base; }
    if (i1 < NBUK) { bukPtr[i1] = base + v0; gCur[i1] = base + v0; }
    if (t == 1023) {
        int tot = s[1023];
        bukPtr[NBUK] = tot;
        ptr[Ntot] = tot;
    }
}

// Pass 1: re-count in LDS, reserve one slice per (block,bucket), scatter
// packed (localrow<<24 | col) via LDS cursors.
__global__ __launch_bounds__(P1T) void pass1_scatter_kernel(
        const int* __restrict__ r0, const int* __restrict__ c0,
        const int* __restrict__ r1, const int* __restrict__ c1,
        const int* __restrict__ r2, const int* __restrict__ c2,
        long long H0, long long H01, long long H, long long E2,
        int off1, int off2, int NBUK,
        int* __restrict__ gCur,
        unsigned* __restrict__ edgeBuf) {
    __shared__ int lcnt[MAXBUK];
    for (int b = threadIdx.x; b < NBUK; b += blockDim.x) lcnt[b] = 0;
    __syncthreads();
    const long long beg = (long long)blockIdx.x * EPB;
    const long long end = (beg + EPB < E2) ? beg + EPB : E2;
    for (long long t = beg + threadIdx.x; t < end; t += blockDim.x) {
        int src, dst;
        decode_edge(t, r0, c0, r1, c1, r2, c2, H0, H01, H, off1, off2, src, dst);
        atomicAdd(&lcnt[src >> 8], 1);
    }
    __syncthreads();
    for (int b = threadIdx.x; b < NBUK; b += blockDim.x) {
        int c = lcnt[b];
        lcnt[b] = c ? atomicAdd(&gCur[b], c) : 0;
    }
    __syncthreads();
    for (long long t = beg + threadIdx.x; t < end; t += blockDim.x) {
        int src, dst;
        decode_edge(t, r0, c0, r1, c1, r2, c2, H0, H01, H, off1, off2, src, dst);
        int pos = atomicAdd(&lcnt[src >> 8], 1);
        edgeBuf[pos] = ((unsigned)(src & 255) << 24) | (unsigned)dst;
    }
}

// Pass 2: one block per bucket. LDS row-hist -> deg/isq/ptr; LDS scan;
// LDS-cursor scatter into ci window; then fused init: curS = bf16(isq*x).
__global__ __launch_bounds__(BWID) void pass2_build_kernel(
        const unsigned* __restrict__ edgeBuf,
        const int* __restrict__ bukPtr,
        int NBUK, int Ntot,
        const float4* __restrict__ fu, const float4* __restrict__ fb,
        const float4* __restrict__ fi,
        int nU, int nB, int off1, int off2,
        int* __restrict__ ptr, float* __restrict__ isq,
        int* __restrict__ ci,
        ushort4* __restrict__ curS) {
    __shared__ int lcnt[BWID];
    __shared__ int lscan[BWID];
    __shared__ float isqv[BWID];
    const int b = blockIdx.x;
    const int t = threadIdx.x;
    const int lo = b * BWID;
    lcnt[t] = 0;
    __syncthreads();
    const int sbeg = bukPtr[b];
    const int send = bukPtr[b + 1];
    for (int p = sbeg + t; p < send; p += BWID) {
        unsigned v = edgeBuf[p];
        atomicAdd(&lcnt[v >> 24], 1);
    }
    __syncthreads();
    const int c = lcnt[t];
    lscan[t] = c;
    __syncthreads();
    for (int off = 1; off < BWID; off <<= 1) {
        int x = (t >= off) ? lscan[t - off] : 0;
        __syncthreads();
        lscan[t] += x;
        __syncthreads();
    }
    const int excl = lscan[t] - c;
    const int node = lo + t;
    const float myIsq = 1.0f / (sqrtf((float)c) + EPS_LAP);
    if (node < Ntot) {
        ptr[node] = sbeg + excl;
        isq[node] = myIsq;
    }
    isqv[t] = myIsq;
    lcnt[t] = sbeg + excl;   // absolute cursor
    __syncthreads();
    for (int p = sbeg + t; p < send; p += BWID) {
        unsigned v = edgeBuf[p];
        int pos = atomicAdd(&lcnt[v >> 24], 1);
        ci[pos] = (int)(v & 0x00FFFFFFu);
    }
    // Fused init: curS = bf16(isq * x) for this bucket's nodes.
    const int nodesHere = (Ntot - lo < BWID) ? (Ntot - lo) : BWID;
    if (nodesHere <= 0) return;
    for (int i = t; i < nodesHere * 16; i += BWID) {
        const int ln = i >> 4;
        const int ch = i & 15;
        const int n = lo + ln;
        float4 v = fetch_feat(fu, fb, fi, nU, nB, off1, off2, n, ch);
        const float q = isqv[ln];
        curS[(long long)n * 16 + ch] =
            make_ushort4(f2b(v.x * q), f2b(v.y * q), f2b(v.z * q), f2b(v.w * q));
    }
}

// Shared gather core: 8 rows/wave, 8 lanes/row, ushort8/lane, 4-way unroll.
#define GATHER_BODY(SRC)                                                      \
    float s0 = 0.f, s1 = 0.f, s2 = 0.f, s3 = 0.f;                             \
    float s4 = 0.f, s5 = 0.f, s6 = 0.f, s7 = 0.f;                             \
    int j = beg;                                                              \
    for (; j + 4 <= end; j += 4) {                                            \
        const unsigned c0 = (unsigned)ci[j];                                  \
        const unsigned c1 = (unsigned)ci[j + 1];                              \
        const unsigned c2 = (unsigned)ci[j + 2];                              \
        const unsigned c3 = (unsigned)ci[j + 3];                              \
        const uint4 v0 = *(const uint4*)(SRC + (c0 << 6) + dof);              \
        const uint4 v1 = *(const uint4*)(SRC + (c1 << 6) + dof);              \
        const uint4 v2 = *(const uint4*)(SRC + (c2 << 6) + dof);              \
        const uint4 v3 = *(const uint4*)(SRC + (c3 << 6) + dof);              \
        s0 += __uint_as_float(v0.x << 16) + __uint_as_float(v1.x << 16)       \
            + __uint_as_float(v2.x << 16) + __uint_as_float(v3.x << 16);      \
        s1 += __uint_as_float(v0.x & 0xffff0000u) + __uint_as_float(v1.x & 0xffff0000u) \
            + __uint_as_float(v2.x & 0xffff0000u) + __uint_as_float(v3.x & 0xffff0000u); \
        s2 += __uint_as_float(v0.y << 16) + __uint_as_float(v1.y << 16)       \
            + __uint_as_float(v2.y << 16) + __uint_as_float(v3.y << 16);      \
        s3 += __uint_as_float(v0.y & 0xffff0000u) + __uint_as_float(v1.y & 0xffff0000u) \
            + __uint_as_float(v2.y & 0xffff0000u) + __uint_as_float(v3.y & 0xffff0000u); \
        s4 += __uint_as_float(v0.z << 16) + __uint_as_float(v1.z << 16)       \
            + __uint_as_float(v2.z << 16) + __uint_as_float(v3.z << 16);      \
        s5 += __uint_as_float(v0.z & 0xffff0000u) + __uint_as_float(v1.z & 0xffff0000u) \
            + __uint_as_float(v2.z & 0xffff0000u) + __uint_as_float(v3.z & 0xffff0000u); \
        s6 += __uint_as_float(v0.w << 16) + __uint_as_float(v1.w << 16)       \
            + __uint_as_float(v2.w << 16) + __uint_as_float(v3.w << 16);      \
        s7 += __uint_as_float(v0.w & 0xffff0000u) + __uint_as_float(v1.w & 0xffff0000u) \
            + __uint_as_float(v2.w & 0xffff0000u) + __uint_as_float(v3.w & 0xffff0000u); \
    }                                                                         \
    for (; j < end; ++j) {                                                    \
        const unsigned cc = (unsigned)ci[j];                                  \
        const uint4 v0 = *(const uint4*)(SRC + (cc << 6) + dof);              \
        s0 += __uint_as_float(v0.x << 16);                                    \
        s1 += __uint_as_float(v0.x & 0xffff0000u);                            \
        s2 += __uint_as_float(v0.y << 16);                                    \
        s3 += __uint_as_float(v0.y & 0xffff0000u);                            \
        s4 += __uint_as_float(v0.z << 16);                                    \
        s5 += __uint_as_float(v0.z & 0xffff0000u);                            \
        s6 += __uint_as_float(v0.w << 16);                                    \
        s7 += __uint_as_float(v0.w & 0xffff0000u);                            \
    }

// Layer 1: raw1 = q*sum; write nxtS = bf16(raw1*q) and nrm1 = ||raw1||.
// No acc traffic.
__global__ void spmm_mid_kernel(const int* __restrict__ ptr,
                                const int* __restrict__ ci,
                                const float* __restrict__ isq,
                                const unsigned short* __restrict__ curS,
                                unsigned short* __restrict__ nxtS,
                                float* __restrict__ nrm1,
                                int N) {
    const long long wid = (blockIdx.x * (long long)blockDim.x + threadIdx.x) >> 6;
    const int lane = threadIdx.x & 63;
    const int row = (int)(wid * 8 + (lane >> 3));
    const unsigned dof = (unsigned)(lane & 7) << 3;
    if (row >= N) return;
    const int beg = ptr[row];
    const int end = ptr[row + 1];
    GATHER_BODY(curS)
    const float q = isq[row];
    const float r0f = s0 * q, r1f = s1 * q, r2f = s2 * q, r3f = s3 * q;
    const float r4f = s4 * q, r5f = s5 * q, r6f = s6 * q, r7f = s7 * q;
    float ss = r0f * r0f + r1f * r1f + r2f * r2f + r3f * r3f
             + r4f * r4f + r5f * r5f + r6f * r6f + r7f * r7f;
    ss += __shfl_xor(ss, 1, 64);
    ss += __shfl_xor(ss, 2, 64);
    ss += __shfl_xor(ss, 4, 64);
    uint4 o;
    o.x = ((unsigned)f2b(r1f * q) << 16) | f2b(r0f * q);
    o.y = ((unsigned)f2b(r3f * q) << 16) | f2b(r2f * q);
    o.z = ((unsigned)f2b(r5f * q) << 16) | f2b(r4f * q);
    o.w = ((unsigned)f2b(r7f * q) << 16) | f2b(r6f * q);
    *(uint4*)(nxtS + ((unsigned)row << 6) + dof) = o;
    if ((lane & 7) == 0) nrm1[row] = sqrtf(ss);
}

// Layer 2 + epilogue: raw2 = q*sum over nxtS; reconstruct raw1 = nxtS_row/q;
// re-read x; out = (x + raw1/max(nrm1,eps) + raw2/max(nrm2,eps)) / 3.
__global__ void spmm_final_kernel(const int* __restrict__ ptr,
                                  const int* __restrict__ ci,
                                  const float* __restrict__ isq,
                                  const unsigned short* __restrict__ cur,
                                  const float* __restrict__ nrm1,
                                  const float4* __restrict__ fu,
                                  const float4* __restrict__ fb,
                                  const float4* __restrict__ fi,
                                  int nU, int nB, int off1, int off2,
                                  float* __restrict__ out,
                                  int N) {
    const long long wid = (blockIdx.x * (long long)blockDim.x + threadIdx.x) >> 6;
    const int lane = threadIdx.x & 63;
    const int row = (int)(wid * 8 + (lane >> 3));
    const unsigned dof = (unsigned)(lane & 7) << 3;
    if (row >= N) return;
    const int beg = ptr[row];
    const int end = ptr[row + 1];
    GATHER_BODY(cur)
    const float q = isq[row];
    const float r0f = s0 * q, r1f = s1 * q, r2f = s2 * q, r3f = s3 * q;
    const float r4f = s4 * q, r5f = s5 * q, r6f = s6 * q, r7f = s7 * q;
    float ss = r0f * r0f + r1f * r1f + r2f * r2f + r3f * r3f
             + r4f * r4f + r5f * r5f + r6f * r6f + r7f * r7f;
    ss += __shfl_xor(ss, 1, 64);
    ss += __shfl_xor(ss, 2, 64);
    ss += __shfl_xor(ss, 4, 64);
    const float sc2 = 1.0f / fmaxf(sqrtf(ss), EPS_NRM);
    const float sc1 = 1.0f / fmaxf(nrm1[row], EPS_NRM);
    const float inv_q = 1.0f / q;
    // own layer-1 row (pre-scaled): raw1 = b2f(nxtS)/q
    const uint4 nx = *(const uint4*)(cur + ((unsigned)row << 6) + dof);
    const int ch = (int)(dof >> 2);       // float4 chunk = dof/4
    const float4 x0 = fetch_feat(fu, fb, fi, nU, nB, off1, off2, row, ch);
    const float4 x1 = fetch_feat(fu, fb, fi, nU, nB, off1, off2, row, ch + 1);
    float4 o0, o1;
    o0.x = (x0.x + __uint_as_float(nx.x << 16)          * inv_q * sc1 + r0f * sc2) * THIRD;
    o0.y = (x0.y + __uint_as_float(nx.x & 0xffff0000u)  * inv_q * sc1 + r1f * sc2) * THIRD;
    o0.z = (x0.z + __uint_as_float(nx.y << 16)          * inv_q * sc1 + r2f * sc2) * THIRD;
    o0.w = (x0.w + __uint_as_float(nx.y & 0xffff0000u)  * inv_q * sc1 + r3f * sc2) * THIRD;
    o1.x = (x1.x + __uint_as_float(nx.z << 16)          * inv_q * sc1 + r4f * sc2) * THIRD;
    o1.y = (x1.y + __uint_as_float(nx.z & 0xffff0000u)  * inv_q * sc1 + r5f * sc2) * THIRD;
    o1.z = (x1.z + __uint_as_float(nx.w << 16)          * inv_q * sc1 + r6f * sc2) * THIRD;
    o1.w = (x1.w + __uint_as_float(nx.w & 0xffff0000u)  * inv_q * sc1 + r7f * sc2) * THIRD;
    float4* op = (float4*)(out + ((long long)row << 6) + dof);
    op[0] = o0;
    op[1] = o1;
}

static inline int grid_for(long long total, int block) {
    long long g = (total + block - 1) / block;
    if (g > (1LL << 20)) g = (1LL << 20);
    if (g < 1) g = 1;
    return (int)g;
}

extern "C" void kernel_launch(void* const* d_in, const int* in_sizes, int n_in,
                              void* d_out, int out_size, void* d_ws, size_t ws_size,
                              hipStream_t stream) {
    const float* fu = (const float*)d_in[0];
    const float* fb = (const float*)d_in[1];
    const float* fi = (const float*)d_in[2];
    const int nU = in_sizes[0] / EMB;
    const int nB = in_sizes[1] / EMB;
    const int nI = in_sizes[2] / EMB;
    float* out = (float*)d_out;

    // Union-graph geometry.
    const int N0 = nU + nB, N1 = nU + nI, N2 = nB + nI;
    const int off1 = N0;
    const int off2 = N0 + N1;
    const int Ntot = N0 + N1 + N2;
    const long long H0 = (long long)in_sizes[3] / 2;
    const long long H1 = (long long)in_sizes[6] / 2;
    const long long H2 = (long long)in_sizes[9] / 2;
    const long long H01 = H0 + H1;
    const long long H = H0 + H1 + H2;
    const long long E2 = 2 * H;
    const int NBUK = (Ntot + BWID - 1) / BWID;
    const int NBLK1 = (int)((E2 + EPB - 1) / EPB);

    const int* r0 = (const int*)d_in[3];
    const int* c0 = (const int*)d_in[4];
    const int* r1 = (const int*)d_in[6];
    const int* c1 = (const int*)d_in[7];
    const int* r2 = (const int*)d_in[9];
    const int* c2 = (const int*)d_in[10];

    // Workspace layout (16B-aligned chunks):
    //   bufA (curS), bufB (nxtS; edgeBuf aliases it — dead before L1 writes),
    //   ptr, isq, nrm1, gBukCnt/bukPtr/gCur, ci.
    char* w = (char*)d_ws;
    unsigned short* bufA = (unsigned short*)w;  w += (size_t)Ntot * EMB * sizeof(unsigned short);
    unsigned short* bufB = (unsigned short*)w;  w += (size_t)Ntot * EMB * sizeof(unsigned short);
    unsigned* edgeBuf = (unsigned*)bufB;        // alias
    int* ptr = (int*)w;                         w += (size_t)((Ntot + 9) & ~7) * sizeof(int);
    float* isq = (float*)w;                     w += (size_t)((Ntot + 8) & ~7) * sizeof(float);
    float* nrm1 = (float*)w;                    w += (size_t)((Ntot + 8) & ~7) * sizeof(float);
    int* gBukCnt = (int*)w;                     w += (size_t)((NBUK + 9) & ~7) * sizeof(int);
    int* bukPtr = (int*)w;                      w += (size_t)((NBUK + 9) & ~7) * sizeof(int);
    int* gCur = (int*)w;                        w += (size_t)((NBUK + 9) & ~7) * sizeof(int);
    int* ci = (int*)w;

    // --- bucketed CSR build + fused init ---
    hipMemsetAsync(gBukCnt, 0, (size_t)NBUK * sizeof(int), stream);
    count_buckets_kernel<<<NBLK1, P1T, 0, stream>>>(
        r0, c0, r1, c1, r2, c2, H0, H01, H, E2, off1, off2, NBUK, gBukCnt);
    scan_buckets_kernel<<<1, 1024, 0, stream>>>(gBukCnt, NBUK, Ntot, bukPtr, gCur, ptr);
    pass1_scatter_kernel<<<NBLK1, P1T, 0, stream>>>(
        r0, c0, r1, c1, r2, c2, H0, H01, H, E2, off1, off2, NBUK, gCur, edgeBuf);
    pass2_build_kernel<<<NBUK, BWID, 0, stream>>>(
        edgeBuf, bukPtr, NBUK, Ntot,
        (const float4*)fu, (const float4*)fb, (const float4*)fi,
        nU, nB, off1, off2,
        ptr, isq, ci, (ushort4*)bufA);

    // --- layer 1 (no acc traffic) + fused layer-2/epilogue ---
    const long long nwaves = ((long long)Ntot + 7) / 8;
    spmm_mid_kernel<<<grid_for(nwaves * 64, 256), 256, 0, stream>>>(
        ptr, ci, isq, bufA, bufB, nrm1, Ntot);
    spmm_final_kernel<<<grid_for(nwaves * 64, 256), 256, 0, stream>>>(
        ptr, ci, isq, bufB, nrm1,
        (const float4*)fu, (const float4*)fb, (const float4*)fi,
        nU, nB, off1, off2, out, Ntot);
}

// Round 15
// 520.119 us; speedup vs baseline: 3.6756x; 1.0309x over previous
//
#include <hip/hip_runtime.h>
#include <hip/hip_bf16.h>

// LightGCN propagation, 3 bipartite graphs. Round 15: pair-based CSR build
// (halve edge-input reads in count/pass1; both directions per thread, LDS
// atomics + slice-local stores) + 8-deep gather unroll probe in spmm.
// Pipeline: bucketed two-pass CSR build (r12) w/ fused init (r14),
// spmm_mid (layer1, no acc traffic) + spmm_final (layer2 + epilogue, single
// out write). Union graph + bf16 features.

constexpr int EMB = 64;
constexpr float THIRD = 1.0f / 3.0f;
constexpr float EPS_NRM = 1e-12f;
constexpr float EPS_LAP = 1e-8f;
constexpr int BWID = 256;            // nodes per bucket (8-bit local row id)
constexpr int MAXBUK = 1536;         // LDS bound: supports Ntot <= 393216
constexpr int PPB = 16384;           // PAIRS per block in count/pass1
constexpr int P1T = 512;             // threads for count/pass1

__device__ __forceinline__ unsigned short f2b(float x) {
    __hip_bfloat16 h = __float2bfloat16(x);
    return *reinterpret_cast<unsigned short*>(&h);
}

// Pair p in [0,H): graph by range; returns endpoints (a,b) in union ids.
__device__ __forceinline__ void decode_pair(
        long long p,
        const int* __restrict__ r0, const int* __restrict__ c0,
        const int* __restrict__ r1, const int* __restrict__ c1,
        const int* __restrict__ r2, const int* __restrict__ c2,
        long long H0, long long H01,
        int off1, int off2, int& a, int& b) {
    if (p < H0)       { a = r0[p];                 b = c0[p]; }
    else if (p < H01) { long long i = p - H0;  a = r1[i] + off1; b = c1[i] + off1; }
    else              { long long i = p - H01; a = r2[i] + off2; b = c2[i] + off2; }
}

// Union feature fetch: node n, float4-chunk ch (0..15).
__device__ __forceinline__ float4 fetch_feat(
        const float4* __restrict__ fu, const float4* __restrict__ fb,
        const float4* __restrict__ fi,
        int nU, int nB, int off1, int off2, int n, int ch) {
    if (n < off1) {
        return (n < nU) ? fu[(long long)n * 16 + ch]
                        : fb[(long long)(n - nU) * 16 + ch];
    } else if (n < off2) {
        int l = n - off1;
        return (l < nU) ? fu[(long long)l * 16 + ch]
                        : fi[(long long)(l - nU) * 16 + ch];
    } else {
        int l = n - off2;
        return (l < nB) ? fb[(long long)l * 16 + ch]
                        : fi[(long long)(l - nB) * 16 + ch];
    }
}

// Pass 0: per-block LDS bucket histogram over PAIRS (both endpoints).
__global__ __launch_bounds__(P1T) void count_buckets_kernel(
        const int* __restrict__ r0, const int* __restrict__ c0,
        const int* __restrict__ r1, const int* __restrict__ c1,
        const int* __restrict__ r2, const int* __restrict__ c2,
        long long H0, long long H01, long long H,
        int off1, int off2, int NBUK,
        int* __restrict__ gBukCnt) {
    __shared__ int lcnt[MAXBUK];
    for (int b = threadIdx.x; b < NBUK; b += blockDim.x) lcnt[b] = 0;
    __syncthreads();
    const long long beg = (long long)blockIdx.x * PPB;
    const long long end = (beg + PPB < H) ? beg + PPB : H;
    for (long long p = beg + threadIdx.x; p < end; p += blockDim.x) {
        int a, b;
        decode_pair(p, r0, c0, r1, c1, r2, c2, H0, H01, off1, off2, a, b);
        atomicAdd(&lcnt[a >> 8], 1);
        atomicAdd(&lcnt[b >> 8], 1);
    }
    __syncthreads();
    for (int b = threadIdx.x; b < NBUK; b += blockDim.x) {
        int c = lcnt[b];
        if (c) atomicAdd(&gBukCnt[b], c);
    }
}

// Scan bucket counts (NBUK <= 2048).
__global__ void scan_buckets_kernel(const int* __restrict__ gBukCnt, int NBUK,
                                    int Ntot,
                                    int* __restrict__ bukPtr,
                                    int* __restrict__ gCur,
                                    int* __restrict__ ptr) {
    __shared__ int s[1024];
    const int t = threadIdx.x;
    const int i0 = 2 * t, i1 = 2 * t + 1;
    int v0 = (i0 < NBUK) ? gBukCnt[i0] : 0;
    int v1 = (i1 < NBUK) ? gBukCnt[i1] : 0;
    int sum = v0 + v1;
    s[t] = sum;
    __syncthreads();
    for (int off = 1; off < 1024; off <<= 1) {
        int x = (t >= off) ? s[t - off] : 0;
        __syncthreads();
        s[t] += x;
        __syncthreads();
    }
    int base = s[t] - sum;
    if (i0 < NBUK) { bukPtr[i0] = base;      gCur[i0] = base; }
    if (i1 < NBUK) { bukPtr[i1] = base + v0; gCur[i1] = base + v0; }
    if (t == 1023) {
        int tot = s[1023];
        bukPtr[NBUK] = tot;
        ptr[Ntot] = tot;
    }
}

// Pass 1 (pair-based): re-count in LDS, reserve one slice per (block,bucket)
// via a single returning atomic, then scatter BOTH directions' packed
// (localrow<<24 | col) records via LDS cursors.
__global__ __launch_bounds__(P1T) void pass1_scatter_kernel(
        const int* __restrict__ r0, const int* __restrict__ c0,
        const int* __restrict__ r1, const int* __restrict__ c1,
        const int* __restrict__ r2, const int* __restrict__ c2,
        long long H0, long long H01, long long H,
        int off1, int off2, int NBUK,
        int* __restrict__ gCur,
        unsigned* __restrict__ edgeBuf) {
    __shared__ int lcnt[MAXBUK];
    for (int b = threadIdx.x; b < NBUK; b += blockDim.x) lcnt[b] = 0;
    __syncthreads();
    const long long beg = (long long)blockIdx.x * PPB;
    const long long end = (beg + PPB < H) ? beg + PPB : H;
    for (long long p = beg + threadIdx.x; p < end; p += blockDim.x) {
        int a, b;
        decode_pair(p, r0, c0, r1, c1, r2, c2, H0, H01, off1, off2, a, b);
        atomicAdd(&lcnt[a >> 8], 1);
        atomicAdd(&lcnt[b >> 8], 1);
    }
    __syncthreads();
    for (int b = threadIdx.x; b < NBUK; b += blockDim.x) {
        int c = lcnt[b];
        lcnt[b] = c ? atomicAdd(&gCur[b], c) : 0;
    }
    __syncthreads();
    for (long long p = beg + threadIdx.x; p < end; p += blockDim.x) {
        int a, b;
        decode_pair(p, r0, c0, r1, c1, r2, c2, H0, H01, off1, off2, a, b);
        int pa = atomicAdd(&lcnt[a >> 8], 1);
        int pb = atomicAdd(&lcnt[b >> 8], 1);
        edgeBuf[pa] = ((unsigned)(a & 255) << 24) | (unsigned)b;
        edgeBuf[pb] = ((unsigned)(b & 255) << 24) | (unsigned)a;
    }
}

// Pass 2: one block per bucket. LDS row-hist -> deg/isq/ptr; LDS scan;
// LDS-cursor scatter into ci window; then fused init: curS = bf16(isq*x).
__global__ __launch_bounds__(BWID) void pass2_build_kernel(
        const unsigned* __restrict__ edgeBuf,
        const int* __restrict__ bukPtr,
        int NBUK, int Ntot,
        const float4* __restrict__ fu, const float4* __restrict__ fb,
        const float4* __restrict__ fi,
        int nU, int nB, int off1, int off2,
        int* __restrict__ ptr, float* __restrict__ isq,
        int* __restrict__ ci,
        ushort4* __restrict__ curS) {
    __shared__ int lcnt[BWID];
    __shared__ int lscan[BWID];
    __shared__ float isqv[BWID];
    const int b = blockIdx.x;
    const int t = threadIdx.x;
    const int lo = b * BWID;
    lcnt[t] = 0;
    __syncthreads();
    const int sbeg = bukPtr[b];
    const int send = bukPtr[b + 1];
    for (int p = sbeg + t; p < send; p += BWID) {
        unsigned v = edgeBuf[p];
        atomicAdd(&lcnt[v >> 24], 1);
    }
    __syncthreads();
    const int c = lcnt[t];
    lscan[t] = c;
    __syncthreads();
    for (int off = 1; off < BWID; off <<= 1) {
        int x = (t >= off) ? lscan[t - off] : 0;
        __syncthreads();
        lscan[t] += x;
        __syncthreads();
    }
    const int excl = lscan[t] - c;
    const int node = lo + t;
    const float myIsq = 1.0f / (sqrtf((float)c) + EPS_LAP);
    if (node < Ntot) {
        ptr[node] = sbeg + excl;
        isq[node] = myIsq;
    }
    isqv[t] = myIsq;
    lcnt[t] = sbeg + excl;   // absolute cursor
    __syncthreads();
    for (int p = sbeg + t; p < send; p += BWID) {
        unsigned v = edgeBuf[p];
        int pos = atomicAdd(&lcnt[v >> 24], 1);
        ci[pos] = (int)(v & 0x00FFFFFFu);
    }
    // Fused init: curS = bf16(isq * x) for this bucket's nodes.
    const int nodesHere = (Ntot - lo < BWID) ? (Ntot - lo) : BWID;
    if (nodesHere <= 0) return;
    for (int i = t; i < nodesHere * 16; i += BWID) {
        const int ln = i >> 4;
        const int ch = i & 15;
        const int n = lo + ln;
        float4 v = fetch_feat(fu, fb, fi, nU, nB, off1, off2, n, ch);
        const float q = isqv[ln];
        curS[(long long)n * 16 + ch] =
            make_ushort4(f2b(v.x * q), f2b(v.y * q), f2b(v.z * q), f2b(v.w * q));
    }
}

// Accumulate one gathered uint4 (8 bf16 dims) into the 8 lane sums.
#define ACC8(V)                                                               \
    s0 += __uint_as_float((V).x << 16);                                       \
    s1 += __uint_as_float((V).x & 0xffff0000u);                               \
    s2 += __uint_as_float((V).y << 16);                                       \
    s3 += __uint_as_float((V).y & 0xffff0000u);                               \
    s4 += __uint_as_float((V).z << 16);                                       \
    s5 += __uint_as_float((V).z & 0xffff0000u);                               \
    s6 += __uint_as_float((V).w << 16);                                       \
    s7 += __uint_as_float((V).w & 0xffff0000u);

// Shared gather core: 8 rows/wave, 8 lanes/row, ushort8/lane, 8-deep unroll.
#define GATHER_BODY(SRC)                                                      \
    float s0 = 0.f, s1 = 0.f, s2 = 0.f, s3 = 0.f;                             \
    float s4 = 0.f, s5 = 0.f, s6 = 0.f, s7 = 0.f;                             \
    int j = beg;                                                              \
    for (; j + 8 <= end; j += 8) {                                            \
        const unsigned c0 = (unsigned)ci[j];                                  \
        const unsigned c1 = (unsigned)ci[j + 1];                              \
        const unsigned c2 = (unsigned)ci[j + 2];                              \
        const unsigned c3 = (unsigned)ci[j + 3];                              \
        const unsigned c4 = (unsigned)ci[j + 4];                              \
        const unsigned c5 = (unsigned)ci[j + 5];                              \
        const unsigned c6 = (unsigned)ci[j + 6];                              \
        const unsigned c7 = (unsigned)ci[j + 7];                              \
        const uint4 v0 = *(const uint4*)(SRC + (c0 << 6) + dof);              \
        const uint4 v1 = *(const uint4*)(SRC + (c1 << 6) + dof);              \
        const uint4 v2 = *(const uint4*)(SRC + (c2 << 6) + dof);              \
        const uint4 v3 = *(const uint4*)(SRC + (c3 << 6) + dof);              \
        const uint4 v4 = *(const uint4*)(SRC + (c4 << 6) + dof);              \
        const uint4 v5 = *(const uint4*)(SRC + (c5 << 6) + dof);              \
        const uint4 v6 = *(const uint4*)(SRC + (c6 << 6) + dof);              \
        const uint4 v7 = *(const uint4*)(SRC + (c7 << 6) + dof);              \
        ACC8(v0) ACC8(v1) ACC8(v2) ACC8(v3)                                   \
        ACC8(v4) ACC8(v5) ACC8(v6) ACC8(v7)                                   \
    }                                                                         \
    for (; j + 2 <= end; j += 2) {                                            \
        const unsigned c0 = (unsigned)ci[j];                                  \
        const unsigned c1 = (unsigned)ci[j + 1];                              \
        const uint4 v0 = *(const uint4*)(SRC + (c0 << 6) + dof);              \
        const uint4 v1 = *(const uint4*)(SRC + (c1 << 6) + dof);              \
        ACC8(v0) ACC8(v1)                                                     \
    }                                                                         \
    if (j < end) {                                                            \
        const unsigned cc = (unsigned)ci[j];                                  \
        const uint4 v0 = *(const uint4*)(SRC + (cc << 6) + dof);              \
        ACC8(v0)                                                              \
    }

// Layer 1: raw1 = q*sum; write nxtS = bf16(raw1*q) and nrm1 = ||raw1||.
__global__ void spmm_mid_kernel(const int* __restrict__ ptr,
                                const int* __restrict__ ci,
                                const float* __restrict__ isq,
                                const unsigned short* __restrict__ curS,
                                unsigned short* __restrict__ nxtS,
                                float* __restrict__ nrm1,
                                int N) {
    const long long wid = (blockIdx.x * (long long)blockDim.x + threadIdx.x) >> 6;
    const int lane = threadIdx.x & 63;
    const int row = (int)(wid * 8 + (lane >> 3));
    const unsigned dof = (unsigned)(lane & 7) << 3;
    if (row >= N) return;
    const int beg = ptr[row];
    const int end = ptr[row + 1];
    GATHER_BODY(curS)
    const float q = isq[row];
    const float r0f = s0 * q, r1f = s1 * q, r2f = s2 * q, r3f = s3 * q;
    const float r4f = s4 * q, r5f = s5 * q, r6f = s6 * q, r7f = s7 * q;
    float ss = r0f * r0f + r1f * r1f + r2f * r2f + r3f * r3f
             + r4f * r4f + r5f * r5f + r6f * r6f + r7f * r7f;
    ss += __shfl_xor(ss, 1, 64);
    ss += __shfl_xor(ss, 2, 64);
    ss += __shfl_xor(ss, 4, 64);
    uint4 o;
    o.x = ((unsigned)f2b(r1f * q) << 16) | f2b(r0f * q);
    o.y = ((unsigned)f2b(r3f * q) << 16) | f2b(r2f * q);
    o.z = ((unsigned)f2b(r5f * q) << 16) | f2b(r4f * q);
    o.w = ((unsigned)f2b(r7f * q) << 16) | f2b(r6f * q);
    *(uint4*)(nxtS + ((unsigned)row << 6) + dof) = o;
    if ((lane & 7) == 0) nrm1[row] = sqrtf(ss);
}

// Layer 2 + epilogue: raw2 = q*sum over nxtS; reconstruct raw1 = nxtS_row/q;
// re-read x; out = (x + raw1/max(nrm1,eps) + raw2/max(nrm2,eps)) / 3.
__global__ void spmm_final_kernel(const int* __restrict__ ptr,
                                  const int* __restrict__ ci,
                                  const float* __restrict__ isq,
                                  const unsigned short* __restrict__ cur,
                                  const float* __restrict__ nrm1,
                                  const float4* __restrict__ fu,
                                  const float4* __restrict__ fb,
                                  const float4* __restrict__ fi,
                                  int nU, int nB, int off1, int off2,
                                  float* __restrict__ out,
                                  int N) {
    const long long wid = (blockIdx.x * (long long)blockDim.x + threadIdx.x) >> 6;
    const int lane = threadIdx.x & 63;
    const int row = (int)(wid * 8 + (lane >> 3));
    const unsigned dof = (unsigned)(lane & 7) << 3;
    if (row >= N) return;
    const int beg = ptr[row];
    const int end = ptr[row + 1];
    GATHER_BODY(cur)
    const float q = isq[row];
    const float r0f = s0 * q, r1f = s1 * q, r2f = s2 * q, r3f = s3 * q;
    const float r4f = s4 * q, r5f = s5 * q, r6f = s6 * q, r7f = s7 * q;
    float ss = r0f * r0f + r1f * r1f + r2f * r2f + r3f * r3f
             + r4f * r4f + r5f * r5f + r6f * r6f + r7f * r7f;
    ss += __shfl_xor(ss, 1, 64);
    ss += __shfl_xor(ss, 2, 64);
    ss += __shfl_xor(ss, 4, 64);
    const float sc2 = 1.0f / fmaxf(sqrtf(ss), EPS_NRM);
    const float sc1 = 1.0f / fmaxf(nrm1[row], EPS_NRM);
    const float inv_q = 1.0f / q;
    const uint4 nx = *(const uint4*)(cur + ((unsigned)row << 6) + dof);
    const int ch = (int)(dof >> 2);
    const float4 x0 = fetch_feat(fu, fb, fi, nU, nB, off1, off2, row, ch);
    const float4 x1 = fetch_feat(fu, fb, fi, nU, nB, off1, off2, row, ch + 1);
    float4 o0, o1;
    o0.x = (x0.x + __uint_as_float(nx.x << 16)          * inv_q * sc1 + r0f * sc2) * THIRD;
    o0.y = (x0.y + __uint_as_float(nx.x & 0xffff0000u)  * inv_q * sc1 + r1f * sc2) * THIRD;
    o0.z = (x0.z + __uint_as_float(nx.y << 16)          * inv_q * sc1 + r2f * sc2) * THIRD;
    o0.w = (x0.w + __uint_as_float(nx.y & 0xffff0000u)  * inv_q * sc1 + r3f * sc2) * THIRD;
    o1.x = (x1.x + __uint_as_float(nx.z << 16)          * inv_q * sc1 + r4f * sc2) * THIRD;
    o1.y = (x1.y + __uint_as_float(nx.z & 0xffff0000u)  * inv_q * sc1 + r5f * sc2) * THIRD;
    o1.z = (x1.z + __uint_as_float(nx.w << 16)          * inv_q * sc1 + r6f * sc2) * THIRD;
    o1.w = (x1.w + __uint_as_float(nx.w & 0xffff0000u)  * inv_q * sc1 + r7f * sc2) * THIRD;
    float4* op = (float4*)(out + ((long long)row << 6) + dof);
    op[0] = o0;
    op[1] = o1;
}

static inline int grid_for(long long total, int block) {
    long long g = (total + block - 1) / block;
    if (g > (1LL << 20)) g = (1LL << 20);
    if (g < 1) g = 1;
    return (int)g;
}

extern "C" void kernel_launch(void* const* d_in, const int* in_sizes, int n_in,
                              void* d_out, int out_size, void* d_ws, size_t ws_size,
                              hipStream_t stream) {
    const float* fu = (const float*)d_in[0];
    const float* fb = (const float*)d_in[1];
    const float* fi = (const float*)d_in[2];
    const int nU = in_sizes[0] / EMB;
    const int nB = in_sizes[1] / EMB;
    const int nI = in_sizes[2] / EMB;
    float* out = (float*)d_out;

    // Union-graph geometry.
    const int N0 = nU + nB, N1 = nU + nI, N2 = nB + nI;
    const int off1 = N0;
    const int off2 = N0 + N1;
    const int Ntot = N0 + N1 + N2;
    const long long H0 = (long long)in_sizes[3] / 2;
    const long long H1 = (long long)in_sizes[6] / 2;
    const long long H2 = (long long)in_sizes[9] / 2;
    const long long H01 = H0 + H1;
    const long long H = H0 + H1 + H2;
    const int NBUK = (Ntot + BWID - 1) / BWID;
    const int NBLK1 = (int)((H + PPB - 1) / PPB);

    const int* r0 = (const int*)d_in[3];
    const int* c0 = (const int*)d_in[4];
    const int* r1 = (const int*)d_in[6];
    const int* c1 = (const int*)d_in[7];
    const int* r2 = (const int*)d_in[9];
    const int* c2 = (const int*)d_in[10];

    // Workspace layout (16B-aligned chunks):
    char* w = (char*)d_ws;
    unsigned short* bufA = (unsigned short*)w;  w += (size_t)Ntot * EMB * sizeof(unsigned short);
    unsigned short* bufB = (unsigned short*)w;  w += (size_t)Ntot * EMB * sizeof(unsigned short);
    unsigned* edgeBuf = (unsigned*)bufB;        // alias (dead until L1 writes)
    int* ptr = (int*)w;                         w += (size_t)((Ntot + 9) & ~7) * sizeof(int);
    float* isq = (float*)w;                     w += (size_t)((Ntot + 8) & ~7) * sizeof(float);
    float* nrm1 = (float*)w;                    w += (size_t)((Ntot + 8) & ~7) * sizeof(float);
    int* gBukCnt = (int*)w;                     w += (size_t)((NBUK + 9) & ~7) * sizeof(int);
    int* bukPtr = (int*)w;                      w += (size_t)((NBUK + 9) & ~7) * sizeof(int);
    int* gCur = (int*)w;                        w += (size_t)((NBUK + 9) & ~7) * sizeof(int);
    int* ci = (int*)w;

    // --- bucketed CSR build (pair-based) + fused init ---
    hipMemsetAsync(gBukCnt, 0, (size_t)NBUK * sizeof(int), stream);
    count_buckets_kernel<<<NBLK1, P1T, 0, stream>>>(
        r0, c0, r1, c1, r2, c2, H0, H01, H, off1, off2, NBUK, gBukCnt);
    scan_buckets_kernel<<<1, 1024, 0, stream>>>(gBukCnt, NBUK, Ntot, bukPtr, gCur, ptr);
    pass1_scatter_kernel<<<NBLK1, P1T, 0, stream>>>(
        r0, c0, r1, c1, r2, c2, H0, H01, H, off1, off2, NBUK, gCur, edgeBuf);
    pass2_build_kernel<<<NBUK, BWID, 0, stream>>>(
        edgeBuf, bukPtr, NBUK, Ntot,
        (const float4*)fu, (const float4*)fb, (const float4*)fi,
        nU, nB, off1, off2,
        ptr, isq, ci, (ushort4*)bufA);

    // --- layer 1 + fused layer-2/epilogue ---
    const long long nwaves = ((long long)Ntot + 7) / 8;
    spmm_mid_kernel<<<grid_for(nwaves * 64, 256), 256, 0, stream>>>(
        ptr, ci, isq, bufA, bufB, nrm1, Ntot);
    spmm_final_kernel<<<grid_for(nwaves * 64, 256), 256, 0, stream>>>(
        ptr, ci, isq, bufB, nrm1,
        (const float4*)fu, (const float4*)fb, (const float4*)fi,
        nU, nB, off1, off2, out, Ntot);
}

// Round 16
// 513.198 us; speedup vs baseline: 3.7252x; 1.0135x over previous
//
#include <hip/hip_runtime.h>
#include <hip/hip_bf16.h>

// LightGCN propagation, 3 bipartite graphs. Round 16: deterministic
// scan-based CSR build. count writes per-(bucket,block) counts to cnt2d
// (no global atomics); a two-level scan over cnt2d (bucket-major) gives
// every block its exact slice base per bucket -> pass1 has NO re-count and
// NO returning atomics. spmm kernels unchanged (fabric-floored at ~3.8TB/s:
// r14 4-deep and r15 8-deep both ~160us).

constexpr int EMB = 64;
constexpr float THIRD = 1.0f / 3.0f;
constexpr float EPS_NRM = 1e-12f;
constexpr float EPS_LAP = 1e-8f;
constexpr int BWID = 256;            // nodes per bucket (8-bit local row id)
constexpr int MAXBUK = 1536;         // LDS bound: supports Ntot <= 393216
constexpr int PPB = 16384;           // PAIRS per block in count/pass1
constexpr int P1T = 512;             // threads for count/pass1
constexpr int SCAN_BLOCK = 256;
constexpr int SCAN_ITEMS = 16;
constexpr int SCAN_TILE = SCAN_BLOCK * SCAN_ITEMS;  // 4096

__device__ __forceinline__ unsigned short f2b(float x) {
    __hip_bfloat16 h = __float2bfloat16(x);
    return *reinterpret_cast<unsigned short*>(&h);
}

// Pair p in [0,H): graph by range; returns endpoints (a,b) in union ids.
__device__ __forceinline__ void decode_pair(
        long long p,
        const int* __restrict__ r0, const int* __restrict__ c0,
        const int* __restrict__ r1, const int* __restrict__ c1,
        const int* __restrict__ r2, const int* __restrict__ c2,
        long long H0, long long H01,
        int off1, int off2, int& a, int& b) {
    if (p < H0)       { a = r0[p];                 b = c0[p]; }
    else if (p < H01) { long long i = p - H0;  a = r1[i] + off1; b = c1[i] + off1; }
    else              { long long i = p - H01; a = r2[i] + off2; b = c2[i] + off2; }
}

// Union feature fetch: node n, float4-chunk ch (0..15).
__device__ __forceinline__ float4 fetch_feat(
        const float4* __restrict__ fu, const float4* __restrict__ fb,
        const float4* __restrict__ fi,
        int nU, int nB, int off1, int off2, int n, int ch) {
    if (n < off1) {
        return (n < nU) ? fu[(long long)n * 16 + ch]
                        : fb[(long long)(n - nU) * 16 + ch];
    } else if (n < off2) {
        int l = n - off1;
        return (l < nU) ? fu[(long long)l * 16 + ch]
                        : fi[(long long)(l - nU) * 16 + ch];
    } else {
        int l = n - off2;
        return (l < nB) ? fb[(long long)l * 16 + ch]
                        : fi[(long long)(l - nB) * 16 + ch];
    }
}

// Pass 0: per-block LDS bucket histogram over PAIRS; write column blk of
// cnt2d[bucket][block] (plain stores, no global atomics).
__global__ __launch_bounds__(P1T) void count_buckets_kernel(
        const int* __restrict__ r0, const int* __restrict__ c0,
        const int* __restrict__ r1, const int* __restrict__ c1,
        const int* __restrict__ r2, const int* __restrict__ c2,
        long long H0, long long H01, long long H,
        int off1, int off2, int NBUK, int NBLK,
        int* __restrict__ cnt2d) {
    __shared__ int lcnt[MAXBUK];
    for (int b = threadIdx.x; b < NBUK; b += blockDim.x) lcnt[b] = 0;
    __syncthreads();
    const long long beg = (long long)blockIdx.x * PPB;
    const long long end = (beg + PPB < H) ? beg + PPB : H;
    for (long long p = beg + threadIdx.x; p < end; p += blockDim.x) {
        int a, b;
        decode_pair(p, r0, c0, r1, c1, r2, c2, H0, H01, off1, off2, a, b);
        atomicAdd(&lcnt[a >> 8], 1);
        atomicAdd(&lcnt[b >> 8], 1);
    }
    __syncthreads();
    for (int b = threadIdx.x; b < NBUK; b += blockDim.x)
        cnt2d[(long long)b * NBLK + blockIdx.x] = lcnt[b];
}

// --- two-level scan over M = NBUK*NBLK (bucket-major) -----------------------
__global__ void scan_partial_kernel(const int* __restrict__ v, int M,
                                    int* __restrict__ bsum) {
    __shared__ int red[SCAN_BLOCK];
    const int b = blockIdx.x;
    const int t = threadIdx.x;
    const int base = b * SCAN_TILE + t * SCAN_ITEMS;
    int s = 0;
    if (base + SCAN_ITEMS <= M) {
        #pragma unroll
        for (int q = 0; q < 4; ++q) {
            int4 a = ((const int4*)v)[(base >> 2) + q];
            s += a.x + a.y + a.z + a.w;
        }
    } else {
        for (int k = 0; k < SCAN_ITEMS; ++k)
            if (base + k < M) s += v[base + k];
    }
    red[t] = s;
    __syncthreads();
    for (int off = SCAN_BLOCK / 2; off > 0; off >>= 1) {
        if (t < off) red[t] += red[t + off];
        __syncthreads();
    }
    if (t == 0) bsum[b] = red[0];
}

__global__ void scan_bsums_kernel(int* __restrict__ bsum, int NB) {
    __shared__ int s[1024];
    const int t = threadIdx.x;
    int v = (t < NB) ? bsum[t] : 0;
    s[t] = v;
    __syncthreads();
    for (int off = 1; off < 1024; off <<= 1) {
        int x = (t >= off) ? s[t - off] : 0;
        __syncthreads();
        s[t] += x;
        __syncthreads();
    }
    if (t < NB) bsum[t] = s[t] - v;      // exclusive prefix
    if (t == 1023) bsum[NB] = s[1023];   // total
}

// Apply: in-place exclusive scan of cnt2d (becomes per-(bucket,block) slice
// bases). Elements at column 0 of a bucket also emit bukPtr[bucket].
__global__ void scan_apply_kernel(int* __restrict__ v, int M,
                                  const int* __restrict__ bsum, int NB,
                                  int NBLK, int NBUK, int Ntot,
                                  int* __restrict__ bukPtr,
                                  int* __restrict__ ptr) {
    __shared__ int tsum[SCAN_BLOCK];
    const int b = blockIdx.x;
    const int t = threadIdx.x;
    const int base = b * SCAN_TILE + t * SCAN_ITEMS;
    int w[SCAN_ITEMS];
    int s = 0;
    if (base + SCAN_ITEMS <= M) {
        #pragma unroll
        for (int q = 0; q < 4; ++q) {
            int4 a = ((const int4*)v)[(base >> 2) + q];
            w[4 * q + 0] = a.x; w[4 * q + 1] = a.y;
            w[4 * q + 2] = a.z; w[4 * q + 3] = a.w;
        }
        #pragma unroll
        for (int k = 0; k < SCAN_ITEMS; ++k) s += w[k];
    } else {
        for (int k = 0; k < SCAN_ITEMS; ++k) {
            w[k] = (base + k < M) ? v[base + k] : 0;
            s += w[k];
        }
    }
    tsum[t] = s;
    __syncthreads();
    for (int off = 1; off < SCAN_BLOCK; off <<= 1) {
        int x = (t >= off) ? tsum[t - off] : 0;
        __syncthreads();
        tsum[t] += x;
        __syncthreads();
    }
    int run = bsum[b] + tsum[t] - s;
    for (int k = 0; k < SCAN_ITEMS; ++k) {
        const int idx = base + k;
        if (idx < M) {
            v[idx] = run;
            if (idx % NBLK == 0) bukPtr[idx / NBLK] = run;
            run += w[k];
        }
    }
    if (b == 0 && t == 0) {
        int tot = bsum[NB];
        bukPtr[NBUK] = tot;
        ptr[Ntot] = tot;
    }
}
// ----------------------------------------------------------------------------

// Pass 1: load this block's cursor column into LDS (exact slice bases from
// the scan), decode pairs once, scatter both directions via LDS cursors.
// No re-count, no returning global atomics.
__global__ __launch_bounds__(P1T) void pass1_scatter_kernel(
        const int* __restrict__ r0, const int* __restrict__ c0,
        const int* __restrict__ r1, const int* __restrict__ c1,
        const int* __restrict__ r2, const int* __restrict__ c2,
        long long H0, long long H01, long long H,
        int off1, int off2, int NBUK, int NBLK,
        const int* __restrict__ cur2d,
        unsigned* __restrict__ edgeBuf) {
    __shared__ int lcnt[MAXBUK];
    for (int b = threadIdx.x; b < NBUK; b += blockDim.x)
        lcnt[b] = cur2d[(long long)b * NBLK + blockIdx.x];
    __syncthreads();
    const long long beg = (long long)blockIdx.x * PPB;
    const long long end = (beg + PPB < H) ? beg + PPB : H;
    for (long long p = beg + threadIdx.x; p < end; p += blockDim.x) {
        int a, b;
        decode_pair(p, r0, c0, r1, c1, r2, c2, H0, H01, off1, off2, a, b);
        int pa = atomicAdd(&lcnt[a >> 8], 1);
        int pb = atomicAdd(&lcnt[b >> 8], 1);
        edgeBuf[pa] = ((unsigned)(a & 255) << 24) | (unsigned)b;
        edgeBuf[pb] = ((unsigned)(b & 255) << 24) | (unsigned)a;
    }
}

// Pass 2: one block per bucket. LDS row-hist -> deg/isq/ptr; LDS scan;
// LDS-cursor scatter into ci window; then fused init: curS = bf16(isq*x).
__global__ __launch_bounds__(BWID) void pass2_build_kernel(
        const unsigned* __restrict__ edgeBuf,
        const int* __restrict__ bukPtr,
        int NBUK, int Ntot,
        const float4* __restrict__ fu, const float4* __restrict__ fb,
        const float4* __restrict__ fi,
        int nU, int nB, int off1, int off2,
        int* __restrict__ ptr, float* __restrict__ isq,
        int* __restrict__ ci,
        ushort4* __restrict__ curS) {
    __shared__ int lcnt[BWID];
    __shared__ int lscan[BWID];
    __shared__ float isqv[BWID];
    const int b = blockIdx.x;
    const int t = threadIdx.x;
    const int lo = b * BWID;
    lcnt[t] = 0;
    __syncthreads();
    const int sbeg = bukPtr[b];
    const int send = bukPtr[b + 1];
    for (int p = sbeg + t; p < send; p += BWID) {
        unsigned v = edgeBuf[p];
        atomicAdd(&lcnt[v >> 24], 1);
    }
    __syncthreads();
    const int c = lcnt[t];
    lscan[t] = c;
    __syncthreads();
    for (int off = 1; off < BWID; off <<= 1) {
        int x = (t >= off) ? lscan[t - off] : 0;
        __syncthreads();
        lscan[t] += x;
        __syncthreads();
    }
    const int excl = lscan[t] - c;
    const int node = lo + t;
    const float myIsq = 1.0f / (sqrtf((float)c) + EPS_LAP);
    if (node < Ntot) {
        ptr[node] = sbeg + excl;
        isq[node] = myIsq;
    }
    isqv[t] = myIsq;
    lcnt[t] = sbeg + excl;   // absolute cursor
    __syncthreads();
    for (int p = sbeg + t; p < send; p += BWID) {
        unsigned v = edgeBuf[p];
        int pos = atomicAdd(&lcnt[v >> 24], 1);
        ci[pos] = (int)(v & 0x00FFFFFFu);
    }
    // Fused init: curS = bf16(isq * x) for this bucket's nodes.
    const int nodesHere = (Ntot - lo < BWID) ? (Ntot - lo) : BWID;
    if (nodesHere <= 0) return;
    for (int i = t; i < nodesHere * 16; i += BWID) {
        const int ln = i >> 4;
        const int ch = i & 15;
        const int n = lo + ln;
        float4 v = fetch_feat(fu, fb, fi, nU, nB, off1, off2, n, ch);
        const float q = isqv[ln];
        curS[(long long)n * 16 + ch] =
            make_ushort4(f2b(v.x * q), f2b(v.y * q), f2b(v.z * q), f2b(v.w * q));
    }
}

// Accumulate one gathered uint4 (8 bf16 dims) into the 8 lane sums.
#define ACC8(V)                                                               \
    s0 += __uint_as_float((V).x << 16);                                       \
    s1 += __uint_as_float((V).x & 0xffff0000u);                               \
    s2 += __uint_as_float((V).y << 16);                                       \
    s3 += __uint_as_float((V).y & 0xffff0000u);                               \
    s4 += __uint_as_float((V).z << 16);                                       \
    s5 += __uint_as_float((V).z & 0xffff0000u);                               \
    s6 += __uint_as_float((V).w << 16);                                       \
    s7 += __uint_as_float((V).w & 0xffff0000u);

// Shared gather core: 8 rows/wave, 8 lanes/row, ushort8/lane, 8-deep unroll.
#define GATHER_BODY(SRC)                                                      \
    float s0 = 0.f, s1 = 0.f, s2 = 0.f, s3 = 0.f;                             \
    float s4 = 0.f, s5 = 0.f, s6 = 0.f, s7 = 0.f;                             \
    int j = beg;                                                              \
    for (; j + 8 <= end; j += 8) {                                            \
        const unsigned c0 = (unsigned)ci[j];                                  \
        const unsigned c1 = (unsigned)ci[j + 1];                              \
        const unsigned c2 = (unsigned)ci[j + 2];                              \
        const unsigned c3 = (unsigned)ci[j + 3];                              \
        const unsigned c4 = (unsigned)ci[j + 4];                              \
        const unsigned c5 = (unsigned)ci[j + 5];                              \
        const unsigned c6 = (unsigned)ci[j + 6];                              \
        const unsigned c7 = (unsigned)ci[j + 7];                              \
        const uint4 v0 = *(const uint4*)(SRC + (c0 << 6) + dof);              \
        const uint4 v1 = *(const uint4*)(SRC + (c1 << 6) + dof);              \
        const uint4 v2 = *(const uint4*)(SRC + (c2 << 6) + dof);              \
        const uint4 v3 = *(const uint4*)(SRC + (c3 << 6) + dof);              \
        const uint4 v4 = *(const uint4*)(SRC + (c4 << 6) + dof);              \
        const uint4 v5 = *(const uint4*)(SRC + (c5 << 6) + dof);              \
        const uint4 v6 = *(const uint4*)(SRC + (c6 << 6) + dof);              \
        const uint4 v7 = *(const uint4*)(SRC + (c7 << 6) + dof);              \
        ACC8(v0) ACC8(v1) ACC8(v2) ACC8(v3)                                   \
        ACC8(v4) ACC8(v5) ACC8(v6) ACC8(v7)                                   \
    }                                                                         \
    for (; j + 2 <= end; j += 2) {                                            \
        const unsigned c0 = (unsigned)ci[j];                                  \
        const unsigned c1 = (unsigned)ci[j + 1];                              \
        const uint4 v0 = *(const uint4*)(SRC + (c0 << 6) + dof);              \
        const uint4 v1 = *(const uint4*)(SRC + (c1 << 6) + dof);              \
        ACC8(v0) ACC8(v1)                                                     \
    }                                                                         \
    if (j < end) {                                                            \
        const unsigned cc = (unsigned)ci[j];                                  \
        const uint4 v0 = *(const uint4*)(SRC + (cc << 6) + dof);              \
        ACC8(v0)                                                              \
    }

// Layer 1: raw1 = q*sum; write nxtS = bf16(raw1*q) and nrm1 = ||raw1||.
__global__ void spmm_mid_kernel(const int* __restrict__ ptr,
                                const int* __restrict__ ci,
                                const float* __restrict__ isq,
                                const unsigned short* __restrict__ curS,
                                unsigned short* __restrict__ nxtS,
                                float* __restrict__ nrm1,
                                int N) {
    const long long wid = (blockIdx.x * (long long)blockDim.x + threadIdx.x) >> 6;
    const int lane = threadIdx.x & 63;
    const int row = (int)(wid * 8 + (lane >> 3));
    const unsigned dof = (unsigned)(lane & 7) << 3;
    if (row >= N) return;
    const int beg = ptr[row];
    const int end = ptr[row + 1];
    GATHER_BODY(curS)
    const float q = isq[row];
    const float r0f = s0 * q, r1f = s1 * q, r2f = s2 * q, r3f = s3 * q;
    const float r4f = s4 * q, r5f = s5 * q, r6f = s6 * q, r7f = s7 * q;
    float ss = r0f * r0f + r1f * r1f + r2f * r2f + r3f * r3f
             + r4f * r4f + r5f * r5f + r6f * r6f + r7f * r7f;
    ss += __shfl_xor(ss, 1, 64);
    ss += __shfl_xor(ss, 2, 64);
    ss += __shfl_xor(ss, 4, 64);
    uint4 o;
    o.x = ((unsigned)f2b(r1f * q) << 16) | f2b(r0f * q);
    o.y = ((unsigned)f2b(r3f * q) << 16) | f2b(r2f * q);
    o.z = ((unsigned)f2b(r5f * q) << 16) | f2b(r4f * q);
    o.w = ((unsigned)f2b(r7f * q) << 16) | f2b(r6f * q);
    *(uint4*)(nxtS + ((unsigned)row << 6) + dof) = o;
    if ((lane & 7) == 0) nrm1[row] = sqrtf(ss);
}

// Layer 2 + epilogue: raw2 = q*sum over nxtS; reconstruct raw1 = nxtS_row/q;
// re-read x; out = (x + raw1/max(nrm1,eps) + raw2/max(nrm2,eps)) / 3.
__global__ void spmm_final_kernel(const int* __restrict__ ptr,
                                  const int* __restrict__ ci,
                                  const float* __restrict__ isq,
                                  const unsigned short* __restrict__ cur,
                                  const float* __restrict__ nrm1,
                                  const float4* __restrict__ fu,
                                  const float4* __restrict__ fb,
                                  const float4* __restrict__ fi,
                                  int nU, int nB, int off1, int off2,
                                  float* __restrict__ out,
                                  int N) {
    const long long wid = (blockIdx.x * (long long)blockDim.x + threadIdx.x) >> 6;
    const int lane = threadIdx.x & 63;
    const int row = (int)(wid * 8 + (lane >> 3));
    const unsigned dof = (unsigned)(lane & 7) << 3;
    if (row >= N) return;
    const int beg = ptr[row];
    const int end = ptr[row + 1];
    GATHER_BODY(cur)
    const float q = isq[row];
    const float r0f = s0 * q, r1f = s1 * q, r2f = s2 * q, r3f = s3 * q;
    const float r4f = s4 * q, r5f = s5 * q, r6f = s6 * q, r7f = s7 * q;
    float ss = r0f * r0f + r1f * r1f + r2f * r2f + r3f * r3f
             + r4f * r4f + r5f * r5f + r6f * r6f + r7f * r7f;
    ss += __shfl_xor(ss, 1, 64);
    ss += __shfl_xor(ss, 2, 64);
    ss += __shfl_xor(ss, 4, 64);
    const float sc2 = 1.0f / fmaxf(sqrtf(ss), EPS_NRM);
    const float sc1 = 1.0f / fmaxf(nrm1[row], EPS_NRM);
    const float inv_q = 1.0f / q;
    const uint4 nx = *(const uint4*)(cur + ((unsigned)row << 6) + dof);
    const int ch = (int)(dof >> 2);
    const float4 x0 = fetch_feat(fu, fb, fi, nU, nB, off1, off2, row, ch);
    const float4 x1 = fetch_feat(fu, fb, fi, nU, nB, off1, off2, row, ch + 1);
    float4 o0, o1;
    o0.x = (x0.x + __uint_as_float(nx.x << 16)          * inv_q * sc1 + r0f * sc2) * THIRD;
    o0.y = (x0.y + __uint_as_float(nx.x & 0xffff0000u)  * inv_q * sc1 + r1f * sc2) * THIRD;
    o0.z = (x0.z + __uint_as_float(nx.y << 16)          * inv_q * sc1 + r2f * sc2) * THIRD;
    o0.w = (x0.w + __uint_as_float(nx.y & 0xffff0000u)  * inv_q * sc1 + r3f * sc2) * THIRD;
    o1.x = (x1.x + __uint_as_float(nx.z << 16)          * inv_q * sc1 + r4f * sc2) * THIRD;
    o1.y = (x1.y + __uint_as_float(nx.z & 0xffff0000u)  * inv_q * sc1 + r5f * sc2) * THIRD;
    o1.z = (x1.z + __uint_as_float(nx.w << 16)          * inv_q * sc1 + r6f * sc2) * THIRD;
    o1.w = (x1.w + __uint_as_float(nx.w & 0xffff0000u)  * inv_q * sc1 + r7f * sc2) * THIRD;
    float4* op = (float4*)(out + ((long long)row << 6) + dof);
    op[0] = o0;
    op[1] = o1;
}

static inline int grid_for(long long total, int block) {
    long long g = (total + block - 1) / block;
    if (g > (1LL << 20)) g = (1LL << 20);
    if (g < 1) g = 1;
    return (int)g;
}

extern "C" void kernel_launch(void* const* d_in, const int* in_sizes, int n_in,
                              void* d_out, int out_size, void* d_ws, size_t ws_size,
                              hipStream_t stream) {
    const float* fu = (const float*)d_in[0];
    const float* fb = (const float*)d_in[1];
    const float* fi = (const float*)d_in[2];
    const int nU = in_sizes[0] / EMB;
    const int nB = in_sizes[1] / EMB;
    const int nI = in_sizes[2] / EMB;
    float* out = (float*)d_out;

    // Union-graph geometry.
    const int N0 = nU + nB, N1 = nU + nI, N2 = nB + nI;
    const int off1 = N0;
    const int off2 = N0 + N1;
    const int Ntot = N0 + N1 + N2;
    const long long H0 = (long long)in_sizes[3] / 2;
    const long long H1 = (long long)in_sizes[6] / 2;
    const long long H2 = (long long)in_sizes[9] / 2;
    const long long H01 = H0 + H1;
    const long long H = H0 + H1 + H2;
    const int NBUK = (Ntot + BWID - 1) / BWID;
    const int NBLK = (int)((H + PPB - 1) / PPB);
    const int M = NBUK * NBLK;                       // cnt2d elements
    const int NB_ = (M + SCAN_TILE - 1) / SCAN_TILE; // scan partial blocks

    const int* r0 = (const int*)d_in[3];
    const int* c0 = (const int*)d_in[4];
    const int* r1 = (const int*)d_in[6];
    const int* c1 = (const int*)d_in[7];
    const int* r2 = (const int*)d_in[9];
    const int* c2 = (const int*)d_in[10];

    // Workspace layout (16B-aligned chunks), ~133MB:
    char* w = (char*)d_ws;
    unsigned short* bufA = (unsigned short*)w;  w += (size_t)Ntot * EMB * sizeof(unsigned short);
    unsigned short* bufB = (unsigned short*)w;  w += (size_t)Ntot * EMB * sizeof(unsigned short);
    unsigned* edgeBuf = (unsigned*)bufB;        // alias (dead until L1 writes)
    int* ptr = (int*)w;                         w += (size_t)((Ntot + 9) & ~7) * sizeof(int);
    float* isq = (float*)w;                     w += (size_t)((Ntot + 8) & ~7) * sizeof(float);
    float* nrm1 = (float*)w;                    w += (size_t)((Ntot + 8) & ~7) * sizeof(float);
    int* cnt2d = (int*)w;                       w += (size_t)((M + 8) & ~7) * sizeof(int);
    int* bukPtr = (int*)w;                      w += (size_t)((NBUK + 9) & ~7) * sizeof(int);
    int* bsum = (int*)w;                        w += (size_t)((NB_ + 9) & ~7) * sizeof(int);
    int* ci = (int*)w;

    // --- deterministic scan-based CSR build + fused init ---
    count_buckets_kernel<<<NBLK, P1T, 0, stream>>>(
        r0, c0, r1, c1, r2, c2, H0, H01, H, off1, off2, NBUK, NBLK, cnt2d);
    scan_partial_kernel<<<NB_, SCAN_BLOCK, 0, stream>>>(cnt2d, M, bsum);
    scan_bsums_kernel<<<1, 1024, 0, stream>>>(bsum, NB_);
    scan_apply_kernel<<<NB_, SCAN_BLOCK, 0, stream>>>(
        cnt2d, M, bsum, NB_, NBLK, NBUK, Ntot, bukPtr, ptr);
    pass1_scatter_kernel<<<NBLK, P1T, 0, stream>>>(
        r0, c0, r1, c1, r2, c2, H0, H01, H, off1, off2, NBUK, NBLK,
        cnt2d, edgeBuf);
    pass2_build_kernel<<<NBUK, BWID, 0, stream>>>(
        edgeBuf, bukPtr, NBUK, Ntot,
        (const float4*)fu, (const float4*)fb, (const float4*)fi,
        nU, nB, off1, off2,
        ptr, isq, ci, (ushort4*)bufA);

    // --- layer 1 + fused layer-2/epilogue ---
    const long long nwaves = ((long long)Ntot + 7) / 8;
    spmm_mid_kernel<<<grid_for(nwaves * 64, 256), 256, 0, stream>>>(
        ptr, ci, isq, bufA, bufB, nrm1, Ntot);
    spmm_final_kernel<<<grid_for(nwaves * 64, 256), 256, 0, stream>>>(
        ptr, ci, isq, bufB, nrm1,
        (const float4*)fu, (const float4*)fb, (const float4*)fi,
        nU, nB, off1, off2, out, Ntot);
}